// Round 1
// baseline (484.816 us; speedup 1.0000x reference)
//
#include <hip/hip_runtime.h>

#define N_NODES   4096
#define E_EDGES   262144
#define IN_DIM    256
#define EDGE_DIM  16
#define NAF       16
#define LATENT    128
#define NBT       5

#define LATENT_OFF 0
#define ATOMS_OFF  (N_NODES * LATENT)                 // 524288
#define BONDS_OFF  (ATOMS_OFF + N_NODES * NAF)        // 589824

#define TBITS 20
#define TSIZE (1u << TBITS)
#define TMASK (TSIZE - 1u)
#define HEMPTY 0xFFFFFFFFu

__device__ __forceinline__ float silu_f(float x) {
    return x / (1.0f + __expf(-x));
}

// ---------------------------------------------------------------------------
// K1: s_act = silu(s @ W_shared^T + b_shared)   (4096 x 256)
// Block: 256 threads = one col each, 16 rows per block. W row kept in regs.
// ---------------------------------------------------------------------------
__global__ __launch_bounds__(256) void k_shared(const float* __restrict__ s,
                                                const float* __restrict__ W,
                                                const float* __restrict__ b,
                                                float* __restrict__ s_act) {
    __shared__ float sl[16][32];
    const int c  = threadIdx.x;
    const int r0 = blockIdx.x * 16;

    float acc[16];
    const float bias = b[c];
#pragma unroll
    for (int r = 0; r < 16; ++r) acc[r] = bias;

    for (int k0 = 0; k0 < IN_DIM; k0 += 32) {
        int idx = c;
        sl[idx >> 5][idx & 31] = s[(r0 + (idx >> 5)) * IN_DIM + k0 + (idx & 31)];
        idx = c + 256;
        sl[idx >> 5][idx & 31] = s[(r0 + (idx >> 5)) * IN_DIM + k0 + (idx & 31)];
        __syncthreads();

        float4 w4[8];
        const float4* wp = (const float4*)(W + c * IN_DIM + k0);
#pragma unroll
        for (int q = 0; q < 8; ++q) w4[q] = wp[q];
        const float* wf = (const float*)w4;
#pragma unroll
        for (int kk = 0; kk < 32; ++kk) {
            const float wv = wf[kk];
#pragma unroll
            for (int r = 0; r < 16; ++r) acc[r] += sl[r][kk] * wv;
        }
        __syncthreads();
    }
#pragma unroll
    for (int r = 0; r < 16; ++r)
        s_act[(r0 + r) * IN_DIM + c] = silu_f(acc[r]);
}

// ---------------------------------------------------------------------------
// K2: atoms_out = s_act @ W_atoms^T + b_atoms   (4096 x 144)
// cols 0..15 -> atoms_pred, cols 16..143 -> latent_pred
// ---------------------------------------------------------------------------
__global__ __launch_bounds__(256) void k_atoms(const float* __restrict__ s_act,
                                               const float* __restrict__ W,
                                               const float* __restrict__ b,
                                               float* __restrict__ out) {
    __shared__ float sl[16][32];
    const int c  = threadIdx.x;
    const int r0 = blockIdx.x * 16;
    const bool active = (c < (NAF + LATENT));

    float acc[16];
    const float bias = active ? b[c] : 0.0f;
#pragma unroll
    for (int r = 0; r < 16; ++r) acc[r] = bias;

    for (int k0 = 0; k0 < IN_DIM; k0 += 32) {
        int idx = c;
        sl[idx >> 5][idx & 31] = s_act[(r0 + (idx >> 5)) * IN_DIM + k0 + (idx & 31)];
        idx = c + 256;
        sl[idx >> 5][idx & 31] = s_act[(r0 + (idx >> 5)) * IN_DIM + k0 + (idx & 31)];
        __syncthreads();

        if (active) {
            float4 w4[8];
            const float4* wp = (const float4*)(W + c * IN_DIM + k0);
#pragma unroll
            for (int q = 0; q < 8; ++q) w4[q] = wp[q];
            const float* wf = (const float*)w4;
#pragma unroll
            for (int kk = 0; kk < 32; ++kk) {
                const float wv = wf[kk];
#pragma unroll
                for (int r = 0; r < 16; ++r) acc[r] += sl[r][kk] * wv;
            }
        }
        __syncthreads();
    }
    if (active) {
#pragma unroll
        for (int r = 0; r < 16; ++r) {
            const int row = r0 + r;
            if (c < NAF) out[ATOMS_OFF + row * NAF + c] = acc[r];
            else         out[LATENT_OFF + row * LATENT + (c - NAF)] = acc[r];
        }
    }
}

// ---------------------------------------------------------------------------
// K3: hash insert — key (j<<12 | i) -> max edge id  (numpy last-wins)
// ---------------------------------------------------------------------------
__global__ __launch_bounds__(256) void k_insert(const int* __restrict__ eidx,
                                                unsigned* __restrict__ keys,
                                                int* __restrict__ vals) {
    const int k = blockIdx.x * blockDim.x + threadIdx.x;
    if (k >= E_EDGES) return;
    const unsigned j = (unsigned)eidx[k];
    const unsigned i = (unsigned)eidx[E_EDGES + k];
    const unsigned key = (j << 12) | i;
    unsigned h = (key * 2654435761u) >> (32 - TBITS);
    while (true) {
        const unsigned old = atomicCAS(&keys[h], HEMPTY, key);
        if (old == HEMPTY || old == key) {
            atomicMax(&vals[h], k);
            break;
        }
        h = (h + 1u) & TMASK;
    }
}

__device__ __forceinline__ int hlookup(const unsigned* __restrict__ keys,
                                       const int* __restrict__ vals,
                                       unsigned key) {
    unsigned h = (key * 2654435761u) >> (32 - TBITS);
    while (true) {
        const unsigned kk = keys[h];
        if (kk == key) return vals[h];
        if (kk == HEMPTY) return -1;
        h = (h + 1u) & TMASK;
    }
}

// ---------------------------------------------------------------------------
// K4: per-edge  f = silu(s[i]+s[j]+e_sym@W_bond^T+b_bond);  bonds = f@W_bonds^T+b
// One wave per edge (grid-stride). Lane l owns cols 4l..4l+3; W_bond rows and
// W_bonds slices preloaded into registers once per thread.
// ---------------------------------------------------------------------------
__global__ __launch_bounds__(256) void k_edges(const int* __restrict__ eidx,
                                               const float* __restrict__ e,
                                               const float* __restrict__ s_act,
                                               const unsigned* __restrict__ keys,
                                               const int* __restrict__ vals,
                                               const float* __restrict__ Wb,
                                               const float* __restrict__ bb,
                                               const float* __restrict__ Wbs,
                                               const float* __restrict__ bbs,
                                               float* __restrict__ out) {
    const int lane   = threadIdx.x & 63;
    const int wave   = (blockIdx.x * blockDim.x + threadIdx.x) >> 6;
    const int nwaves = (gridDim.x * blockDim.x) >> 6;
    const int cbase  = lane * 4;

    // per-thread constant preloads (registers)
    float wbond[4][16];
#pragma unroll
    for (int r = 0; r < 4; ++r) {
        const float4* wp = (const float4*)(Wb + (cbase + r) * EDGE_DIM);
#pragma unroll
        for (int d4 = 0; d4 < 4; ++d4) {
            const float4 v = wp[d4];
            wbond[r][d4 * 4 + 0] = v.x;
            wbond[r][d4 * 4 + 1] = v.y;
            wbond[r][d4 * 4 + 2] = v.z;
            wbond[r][d4 * 4 + 3] = v.w;
        }
    }
    float wbs[NBT][4];
#pragma unroll
    for (int q = 0; q < NBT; ++q) {
        const float4 v = *(const float4*)(Wbs + q * IN_DIM + cbase);
        wbs[q][0] = v.x; wbs[q][1] = v.y; wbs[q][2] = v.z; wbs[q][3] = v.w;
    }
    float bias[4];
    {
        const float4 v = *(const float4*)(bb + cbase);
        bias[0] = v.x; bias[1] = v.y; bias[2] = v.z; bias[3] = v.w;
    }
    float bb5[NBT];
#pragma unroll
    for (int q = 0; q < NBT; ++q) bb5[q] = bbs[q];

    for (int k = wave; k < E_EDGES; k += nwaves) {
        const unsigned j = (unsigned)eidx[k];
        const unsigned i = (unsigned)eidx[E_EDGES + k];

        const int wf = hlookup(keys, vals, (j << 12) | i);   // always found
        const int wr = hlookup(keys, vals, (i << 12) | j);   // may be -1

        float es[16];
        {
            const float4* ef = (const float4*)(e + (size_t)wf * EDGE_DIM);
#pragma unroll
            for (int d4 = 0; d4 < 4; ++d4) {
                const float4 v = ef[d4];
                es[d4 * 4 + 0] = v.x; es[d4 * 4 + 1] = v.y;
                es[d4 * 4 + 2] = v.z; es[d4 * 4 + 3] = v.w;
            }
            if (wr >= 0) {
                const float4* er = (const float4*)(e + (size_t)wr * EDGE_DIM);
#pragma unroll
                for (int d4 = 0; d4 < 4; ++d4) {
                    const float4 v = er[d4];
                    es[d4 * 4 + 0] += v.x; es[d4 * 4 + 1] += v.y;
                    es[d4 * 4 + 2] += v.z; es[d4 * 4 + 3] += v.w;
                }
            }
#pragma unroll
            for (int d = 0; d < 16; ++d) es[d] *= 0.5f;
        }

        const float4 si = *(const float4*)(s_act + (size_t)i * IN_DIM + cbase);
        const float4 sj = *(const float4*)(s_act + (size_t)j * IN_DIM + cbase);
        const float sif[4] = {si.x, si.y, si.z, si.w};
        const float sjf[4] = {sj.x, sj.y, sj.z, sj.w};

        float f[4];
#pragma unroll
        for (int r = 0; r < 4; ++r) {
            float t = bias[r] + sif[r] + sjf[r];
#pragma unroll
            for (int d = 0; d < 16; ++d) t += es[d] * wbond[r][d];
            f[r] = silu_f(t);
        }

#pragma unroll
        for (int q = 0; q < NBT; ++q) {
            float v = f[0] * wbs[q][0] + f[1] * wbs[q][1] +
                      f[2] * wbs[q][2] + f[3] * wbs[q][3];
#pragma unroll
            for (int off = 32; off > 0; off >>= 1) v += __shfl_xor(v, off, 64);
            if (lane == 0) out[BONDS_OFF + (size_t)k * NBT + q] = v + bb5[q];
        }
    }
}

// ---------------------------------------------------------------------------
extern "C" void kernel_launch(void* const* d_in, const int* in_sizes, int n_in,
                              void* d_out, int out_size, void* d_ws, size_t ws_size,
                              hipStream_t stream) {
    const float* s   = (const float*)d_in[0];
    const float* e   = (const float*)d_in[1];
    // d_in[2] = batch (unused)
    const int*   eix = (const int*)d_in[3];
    const float* Wsh = (const float*)d_in[4];
    const float* bsh = (const float*)d_in[5];
    const float* Wb  = (const float*)d_in[6];
    const float* bbo = (const float*)d_in[7];
    const float* Wbs = (const float*)d_in[8];
    const float* bbs = (const float*)d_in[9];
    const float* Wa  = (const float*)d_in[10];
    const float* ba  = (const float*)d_in[11];
    float* out = (float*)d_out;

    char* ws = (char*)d_ws;
    float*    s_act = (float*)ws;                    // 4 MB
    unsigned* keys  = (unsigned*)(ws + (4u << 20));  // 4 MB
    int*      vals  = (int*)(ws + (8u << 20));       // 4 MB

    hipMemsetAsync(keys, 0xFF, TSIZE * sizeof(unsigned), stream);
    hipMemsetAsync(vals, 0x00, TSIZE * sizeof(int), stream);

    k_shared<<<N_NODES / 16, 256, 0, stream>>>(s, Wsh, bsh, s_act);
    k_insert<<<E_EDGES / 256, 256, 0, stream>>>(eix, keys, vals);
    k_atoms<<<N_NODES / 16, 256, 0, stream>>>(s_act, Wa, ba, out);
    k_edges<<<4096, 256, 0, stream>>>(eix, e, s_act, keys, vals,
                                      Wb, bbo, Wbs, bbs, out);
}

// Round 3
// 333.533 us; speedup vs baseline: 1.4536x; 1.4536x over previous
//
#include <hip/hip_runtime.h>

#define N_NODES   4096
#define E_EDGES   262144
#define IN_DIM    256
#define EDGE_DIM  16
#define NAF       16
#define LATENT    128
#define NBT       5

#define LATENT_OFF 0
#define ATOMS_OFF  (N_NODES * LATENT)                 // 524288
#define BONDS_OFF  (ATOMS_OFF + N_NODES * NAF)        // 589824

#define TBITS 20
#define TSIZE (1u << TBITS)
#define TMASK (TSIZE - 1u)

typedef float f32x4 __attribute__((ext_vector_type(4)));

__device__ __forceinline__ float silu_f(float x) {
    return x / (1.0f + __expf(-x));
}

// ---------------------------------------------------------------------------
// K12: s_act = silu(s @ W_shared^T + b);  atoms_out = s_act @ W_atoms^T + b
// Fused: block computes 16 rows of s_act (kept in LDS) then atoms directly.
// ---------------------------------------------------------------------------
__global__ __launch_bounds__(256) void k12(const float* __restrict__ s,
                                           const float* __restrict__ Wsh,
                                           const float* __restrict__ bsh,
                                           const float* __restrict__ Wa,
                                           const float* __restrict__ ba,
                                           float* __restrict__ s_act,
                                           float* __restrict__ out) {
    __shared__ float sl[16][32];
    __shared__ float st[16][IN_DIM];
    const int c  = threadIdx.x;
    const int r0 = blockIdx.x * 16;

    // ---- phase 1: s_act rows r0..r0+15 ----
    float acc[16];
    const float bias = bsh[c];
#pragma unroll
    for (int r = 0; r < 16; ++r) acc[r] = bias;

    for (int k0 = 0; k0 < IN_DIM; k0 += 32) {
        int idx = c;
        sl[idx >> 5][idx & 31] = s[(r0 + (idx >> 5)) * IN_DIM + k0 + (idx & 31)];
        idx = c + 256;
        sl[idx >> 5][idx & 31] = s[(r0 + (idx >> 5)) * IN_DIM + k0 + (idx & 31)];
        __syncthreads();

        float4 w4[8];
        const float4* wp = (const float4*)(Wsh + c * IN_DIM + k0);
#pragma unroll
        for (int q = 0; q < 8; ++q) w4[q] = wp[q];
        const float* wf = (const float*)w4;
#pragma unroll
        for (int r = 0; r < 16; ++r) {
            const float4* srow = (const float4*)sl[r];
            float a = acc[r];
#pragma unroll
            for (int q = 0; q < 8; ++q) {
                const float4 sv = srow[q];
                a += sv.x * wf[q * 4 + 0];
                a += sv.y * wf[q * 4 + 1];
                a += sv.z * wf[q * 4 + 2];
                a += sv.w * wf[q * 4 + 3];
            }
            acc[r] = a;
        }
        __syncthreads();
    }
#pragma unroll
    for (int r = 0; r < 16; ++r) {
        const float v = silu_f(acc[r]);
        s_act[(r0 + r) * IN_DIM + c] = v;
        st[r][c] = v;
    }
    __syncthreads();

    // ---- phase 2: atoms_out rows r0..r0+15, cols 0..143 ----
    const bool active = (c < (NAF + LATENT));
    float acc2[16];
    const float bias2 = active ? ba[c] : 0.0f;
#pragma unroll
    for (int r = 0; r < 16; ++r) acc2[r] = bias2;

    if (active) {
        for (int k0 = 0; k0 < IN_DIM; k0 += 32) {
            float4 w4[8];
            const float4* wp = (const float4*)(Wa + c * IN_DIM + k0);
#pragma unroll
            for (int q = 0; q < 8; ++q) w4[q] = wp[q];
            const float* wf = (const float*)w4;
#pragma unroll
            for (int r = 0; r < 16; ++r) {
                const float4* srow = (const float4*)(st[r] + k0);
                float a = acc2[r];
#pragma unroll
                for (int q = 0; q < 8; ++q) {
                    const float4 sv = srow[q];
                    a += sv.x * wf[q * 4 + 0];
                    a += sv.y * wf[q * 4 + 1];
                    a += sv.z * wf[q * 4 + 2];
                    a += sv.w * wf[q * 4 + 3];
                }
                acc2[r] = a;
            }
        }
#pragma unroll
        for (int r = 0; r < 16; ++r) {
            const int row = r0 + r;
            if (c < NAF) out[ATOMS_OFF + row * NAF + c] = acc2[r];
            else         out[LATENT_OFF + row * LATENT + (c - NAF)] = acc2[r];
        }
    }
}

// ---------------------------------------------------------------------------
// K3: hash insert — slot u64 = ((key+1)<<18) | edge_id, winner = max edge_id
// key = (j<<12)|i (24 bits), edge_id 18 bits. Empty slot = 0.
// ---------------------------------------------------------------------------
__global__ __launch_bounds__(256) void k_insert(const int* __restrict__ eidx,
                                                unsigned long long* __restrict__ tab) {
    const int k = blockIdx.x * blockDim.x + threadIdx.x;
    const unsigned j = (unsigned)eidx[k];
    const unsigned i = (unsigned)eidx[E_EDGES + k];
    const unsigned key = (j << 12) | i;
    const unsigned long long mine =
        ((unsigned long long)(key + 1u) << 18) | (unsigned)k;
    unsigned h = (key * 2654435761u) >> (32 - TBITS);
    while (true) {
        unsigned long long cur = tab[h];
        if (cur == 0ULL) {
            const unsigned long long old = atomicCAS(&tab[h], 0ULL, mine);
            if (old == 0ULL) return;
            cur = old;
        }
        if ((unsigned)(cur >> 18) == key + 1u) {
            atomicMax(&tab[h], mine);
            return;
        }
        h = (h + 1u) & TMASK;
    }
}

__device__ __forceinline__ int hlookup(const unsigned long long* __restrict__ tab,
                                       unsigned key) {
    unsigned h = (key * 2654435761u) >> (32 - TBITS);
    while (true) {
        const unsigned long long cur = tab[h];
        if (cur == 0ULL) return -1;
        if ((unsigned)(cur >> 18) == key + 1u) return (int)(cur & 0x3FFFFu);
        h = (h + 1u) & TMASK;
    }
}

// ---------------------------------------------------------------------------
// K4a: resolve hash per edge, write esym[k][16] = 0.5*(e[fwd] + e[rev])
// One thread per edge; massive TLP hides probe latency.
// ---------------------------------------------------------------------------
__global__ __launch_bounds__(256) void k_esym(const int* __restrict__ eidx,
                                              const float* __restrict__ e,
                                              const unsigned long long* __restrict__ tab,
                                              float* __restrict__ esym) {
    const int k = blockIdx.x * blockDim.x + threadIdx.x;
    const unsigned j = (unsigned)eidx[k];
    const unsigned i = (unsigned)eidx[E_EDGES + k];
    const int wf = hlookup(tab, (j << 12) | i);   // always found
    const int wr = hlookup(tab, (i << 12) | j);   // may be -1

    const f32x4* ef = (const f32x4*)(e + (size_t)wf * EDGE_DIM);
    f32x4 a0 = __builtin_nontemporal_load(ef + 0);
    f32x4 a1 = __builtin_nontemporal_load(ef + 1);
    f32x4 a2 = __builtin_nontemporal_load(ef + 2);
    f32x4 a3 = __builtin_nontemporal_load(ef + 3);
    if (wr >= 0) {
        const f32x4* er = (const f32x4*)(e + (size_t)wr * EDGE_DIM);
        a0 += __builtin_nontemporal_load(er + 0);
        a1 += __builtin_nontemporal_load(er + 1);
        a2 += __builtin_nontemporal_load(er + 2);
        a3 += __builtin_nontemporal_load(er + 3);
    }
    a0 *= 0.5f; a1 *= 0.5f; a2 *= 0.5f; a3 *= 0.5f;

    f32x4* dst = (f32x4*)(esym + (size_t)k * EDGE_DIM);
    __builtin_nontemporal_store(a0, dst + 0);
    __builtin_nontemporal_store(a1, dst + 1);
    __builtin_nontemporal_store(a2, dst + 2);
    __builtin_nontemporal_store(a3, dst + 3);
}

// ---------------------------------------------------------------------------
// K4b: streaming edge kernel (no hash).
// f = silu(s[i]+s[j]+esym@Wb^T+bb);  bonds = f@Wbs^T+bbs
// One wave per edge-pair iteration; wave-uniform data scalarized.
// ---------------------------------------------------------------------------
#define EPW 16   // edges per wave; grid fixed at 4096 blocks x 256

__global__ __launch_bounds__(256, 4) void k_edges2(const int* __restrict__ eidx,
                                                   const float* __restrict__ esym,
                                                   const float* __restrict__ s_act,
                                                   const float* __restrict__ Wb,
                                                   const float* __restrict__ bb,
                                                   const float* __restrict__ Wbs,
                                                   const float* __restrict__ bbs,
                                                   float* __restrict__ out) {
    const int lane  = threadIdx.x & 63;
    const int wave  = (blockIdx.x * blockDim.x + threadIdx.x) >> 6;
    const int base  = __builtin_amdgcn_readfirstlane(wave * EPW);
    const int cbase = lane * 4;

    // per-lane constants
    float wbond[4][16];
#pragma unroll
    for (int r = 0; r < 4; ++r) {
        const float4* wp = (const float4*)(Wb + (cbase + r) * EDGE_DIM);
#pragma unroll
        for (int d4 = 0; d4 < 4; ++d4) {
            const float4 v = wp[d4];
            wbond[r][d4 * 4 + 0] = v.x; wbond[r][d4 * 4 + 1] = v.y;
            wbond[r][d4 * 4 + 2] = v.z; wbond[r][d4 * 4 + 3] = v.w;
        }
    }
    float wbs[NBT][4];
#pragma unroll
    for (int q = 0; q < NBT; ++q) {
        const float4 v = *(const float4*)(Wbs + q * IN_DIM + cbase);
        wbs[q][0] = v.x; wbs[q][1] = v.y; wbs[q][2] = v.z; wbs[q][3] = v.w;
    }
    float bias[4];
    {
        const float4 v = *(const float4*)(bb + cbase);
        bias[0] = v.x; bias[1] = v.y; bias[2] = v.z; bias[3] = v.w;
    }
    float bb5[NBT];
#pragma unroll
    for (int q = 0; q < NBT; ++q) bb5[q] = bbs[q];

#pragma unroll 2
    for (int t = 0; t < EPW; t += 2) {
        const int k0 = base + t;
        const int k1 = base + t + 1;

        // wave-uniform loads (scalarized: base is readfirstlane'd)
        const int j0 = eidx[k0];
        const int i0 = eidx[E_EDGES + k0];
        const int j1 = eidx[k1];
        const int i1 = eidx[E_EDGES + k1];

        float es0[16], es1[16];
#pragma unroll
        for (int d = 0; d < 16; ++d) es0[d] = esym[(size_t)k0 * EDGE_DIM + d];
#pragma unroll
        for (int d = 0; d < 16; ++d) es1[d] = esym[(size_t)k1 * EDGE_DIM + d];

        const float4 si0 = *(const float4*)(s_act + (size_t)i0 * IN_DIM + cbase);
        const float4 sj0 = *(const float4*)(s_act + (size_t)j0 * IN_DIM + cbase);
        const float4 si1 = *(const float4*)(s_act + (size_t)i1 * IN_DIM + cbase);
        const float4 sj1 = *(const float4*)(s_act + (size_t)j1 * IN_DIM + cbase);

        const float s0f[4] = {si0.x + sj0.x, si0.y + sj0.y, si0.z + sj0.z, si0.w + sj0.w};
        const float s1f[4] = {si1.x + sj1.x, si1.y + sj1.y, si1.z + sj1.z, si1.w + sj1.w};

        float f0[4], f1[4];
#pragma unroll
        for (int r = 0; r < 4; ++r) {
            float t0 = bias[r] + s0f[r];
            float t1 = bias[r] + s1f[r];
#pragma unroll
            for (int d = 0; d < 16; ++d) {
                t0 += es0[d] * wbond[r][d];
                t1 += es1[d] * wbond[r][d];
            }
            f0[r] = silu_f(t0);
            f1[r] = silu_f(t1);
        }

        float p0[NBT], p1[NBT];
#pragma unroll
        for (int q = 0; q < NBT; ++q) {
            p0[q] = f0[0] * wbs[q][0] + f0[1] * wbs[q][1] +
                    f0[2] * wbs[q][2] + f0[3] * wbs[q][3];
            p1[q] = f1[0] * wbs[q][0] + f1[1] * wbs[q][1] +
                    f1[2] * wbs[q][2] + f1[3] * wbs[q][3];
        }
#pragma unroll
        for (int off = 32; off > 0; off >>= 1) {
#pragma unroll
            for (int q = 0; q < NBT; ++q) {
                p0[q] += __shfl_xor(p0[q], off, 64);
                p1[q] += __shfl_xor(p1[q], off, 64);
            }
        }

        float v0 = p0[0] + bb5[0];
        v0 = (lane == 1) ? p0[1] + bb5[1] : v0;
        v0 = (lane == 2) ? p0[2] + bb5[2] : v0;
        v0 = (lane == 3) ? p0[3] + bb5[3] : v0;
        v0 = (lane == 4) ? p0[4] + bb5[4] : v0;
        float v1 = p1[0] + bb5[0];
        v1 = (lane == 1) ? p1[1] + bb5[1] : v1;
        v1 = (lane == 2) ? p1[2] + bb5[2] : v1;
        v1 = (lane == 3) ? p1[3] + bb5[3] : v1;
        v1 = (lane == 4) ? p1[4] + bb5[4] : v1;
        if (lane < 5) {
            __builtin_nontemporal_store(v0, &out[BONDS_OFF + (size_t)k0 * NBT + lane]);
            __builtin_nontemporal_store(v1, &out[BONDS_OFF + (size_t)k1 * NBT + lane]);
        }
    }
}

// ---------------------------------------------------------------------------
extern "C" void kernel_launch(void* const* d_in, const int* in_sizes, int n_in,
                              void* d_out, int out_size, void* d_ws, size_t ws_size,
                              hipStream_t stream) {
    const float* s   = (const float*)d_in[0];
    const float* e   = (const float*)d_in[1];
    const int*   eix = (const int*)d_in[3];
    const float* Wsh = (const float*)d_in[4];
    const float* bsh = (const float*)d_in[5];
    const float* Wb  = (const float*)d_in[6];
    const float* bbo = (const float*)d_in[7];
    const float* Wbs = (const float*)d_in[8];
    const float* bbs = (const float*)d_in[9];
    const float* Wa  = (const float*)d_in[10];
    const float* ba  = (const float*)d_in[11];
    float* out = (float*)d_out;

    char* ws = (char*)d_ws;
    float*              s_act = (float*)ws;                     // 4 MB
    unsigned long long* tab   = (unsigned long long*)(ws + (4u << 20));  // 8 MB
    float*              esym  = (float*)(ws + (12u << 20));     // 16 MB

    (void)hipMemsetAsync(tab, 0x00, TSIZE * sizeof(unsigned long long), stream);

    k_insert<<<E_EDGES / 256, 256, 0, stream>>>(eix, tab);
    k12<<<N_NODES / 16, 256, 0, stream>>>(s, Wsh, bsh, Wa, ba, s_act, out);
    k_esym<<<E_EDGES / 256, 256, 0, stream>>>(eix, e, tab, esym);
    k_edges2<<<4096, 256, 0, stream>>>(eix, esym, s_act, Wb, bbo, Wbs, bbs, out);
}

// Round 4
// 282.330 us; speedup vs baseline: 1.7172x; 1.1814x over previous
//
#include <hip/hip_runtime.h>

#define N_NODES   4096
#define E_EDGES   262144
#define IN_DIM    256
#define EDGE_DIM  16
#define NAF       16
#define LATENT    128
#define NBT       5

#define LATENT_OFF 0
#define ATOMS_OFF  (N_NODES * LATENT)                 // 524288
#define BONDS_OFF  (ATOMS_OFF + N_NODES * NAF)        // 589824

// hash fallback
#define TBITS 20
#define TSIZE (1u << TBITS)
#define TMASK (TSIZE - 1u)

// direct table: 2^24 u32 entries = 64 MB
#define DKEYS (1u << 24)

typedef float f32x4 __attribute__((ext_vector_type(4)));

__device__ __forceinline__ float silu_f(float x) {
    return x / (1.0f + __expf(-x));
}

// ---------------------------------------------------------------------------
// K12: s_act = silu(s @ W_shared^T + b);  atoms_out = s_act @ W_atoms^T + b
// 8 rows/block (512 blocks -> 2 blocks/CU) for wave overlap.
// ---------------------------------------------------------------------------
__global__ __launch_bounds__(256) void k12(const float* __restrict__ s,
                                           const float* __restrict__ Wsh,
                                           const float* __restrict__ bsh,
                                           const float* __restrict__ Wa,
                                           const float* __restrict__ ba,
                                           float* __restrict__ s_act,
                                           float* __restrict__ out) {
    __shared__ float sl[8][32];
    __shared__ float st[8][IN_DIM];
    const int c  = threadIdx.x;
    const int r0 = blockIdx.x * 8;

    // ---- phase 1: s_act rows r0..r0+7 ----
    float acc[8];
    const float bias = bsh[c];
#pragma unroll
    for (int r = 0; r < 8; ++r) acc[r] = bias;

    for (int k0 = 0; k0 < IN_DIM; k0 += 32) {
        sl[c >> 5][c & 31] = s[(r0 + (c >> 5)) * IN_DIM + k0 + (c & 31)];
        __syncthreads();

        float4 w4[8];
        const float4* wp = (const float4*)(Wsh + c * IN_DIM + k0);
#pragma unroll
        for (int q = 0; q < 8; ++q) w4[q] = wp[q];
        const float* wf = (const float*)w4;
#pragma unroll
        for (int r = 0; r < 8; ++r) {
            const float4* srow = (const float4*)sl[r];
            float a = acc[r];
#pragma unroll
            for (int q = 0; q < 8; ++q) {
                const float4 sv = srow[q];
                a += sv.x * wf[q * 4 + 0];
                a += sv.y * wf[q * 4 + 1];
                a += sv.z * wf[q * 4 + 2];
                a += sv.w * wf[q * 4 + 3];
            }
            acc[r] = a;
        }
        __syncthreads();
    }
#pragma unroll
    for (int r = 0; r < 8; ++r) {
        const float v = silu_f(acc[r]);
        s_act[(r0 + r) * IN_DIM + c] = v;
        st[r][c] = v;
    }
    __syncthreads();

    // ---- phase 2: atoms_out rows r0..r0+7, cols 0..143 ----
    const bool active = (c < (NAF + LATENT));
    float acc2[8];
    const float bias2 = active ? ba[c] : 0.0f;
#pragma unroll
    for (int r = 0; r < 8; ++r) acc2[r] = bias2;

    if (active) {
        for (int k0 = 0; k0 < IN_DIM; k0 += 32) {
            float4 w4[8];
            const float4* wp = (const float4*)(Wa + c * IN_DIM + k0);
#pragma unroll
            for (int q = 0; q < 8; ++q) w4[q] = wp[q];
            const float* wf = (const float*)w4;
#pragma unroll
            for (int r = 0; r < 8; ++r) {
                const float4* srow = (const float4*)(st[r] + k0);
                float a = acc2[r];
#pragma unroll
                for (int q = 0; q < 8; ++q) {
                    const float4 sv = srow[q];
                    a += sv.x * wf[q * 4 + 0];
                    a += sv.y * wf[q * 4 + 1];
                    a += sv.z * wf[q * 4 + 2];
                    a += sv.w * wf[q * 4 + 3];
                }
                acc2[r] = a;
            }
        }
#pragma unroll
        for (int r = 0; r < 8; ++r) {
            const int row = r0 + r;
            if (c < NAF) out[ATOMS_OFF + row * NAF + c] = acc2[r];
            else         out[LATENT_OFF + row * LATENT + (c - NAF)] = acc2[r];
        }
    }
}

// ---------------------------------------------------------------------------
// Direct-table path: T[key] = max(edge_id+1), key = (j<<12)|i.  Empty = 0.
// ---------------------------------------------------------------------------
__global__ __launch_bounds__(256) void k_insert_d(const int* __restrict__ eidx,
                                                  unsigned* __restrict__ T) {
    const int k = blockIdx.x * blockDim.x + threadIdx.x;
    const unsigned j = (unsigned)eidx[k];
    const unsigned i = (unsigned)eidx[E_EDGES + k];
    atomicMax(&T[(j << 12) | i], (unsigned)(k + 1));
}

__global__ __launch_bounds__(256) void k_esym_d(const int* __restrict__ eidx,
                                                const float* __restrict__ e,
                                                const unsigned* __restrict__ T,
                                                float* __restrict__ esym) {
    const int k = blockIdx.x * blockDim.x + threadIdx.x;
    const unsigned j = (unsigned)eidx[k];
    const unsigned i = (unsigned)eidx[E_EDGES + k];

    // coalesced own-row load (winner for ~98.4% of edges)
    const f32x4* eo = (const f32x4*)(e + (size_t)k * EDGE_DIM);
    f32x4 a0 = eo[0], a1 = eo[1], a2 = eo[2], a3 = eo[3];

    const unsigned wf = T[(j << 12) | i];   // >= 1 always
    const unsigned wr = T[(i << 12) | j];   // 0 if absent

    if ((int)(wf - 1u) != k) {              // rare duplicate-loser path
        const f32x4* ef = (const f32x4*)(e + (size_t)(wf - 1u) * EDGE_DIM);
        a0 = ef[0]; a1 = ef[1]; a2 = ef[2]; a3 = ef[3];
    }
    if (wr != 0u) {
        const f32x4* er = (const f32x4*)(e + (size_t)(wr - 1u) * EDGE_DIM);
        a0 += er[0]; a1 += er[1]; a2 += er[2]; a3 += er[3];
    }
    a0 *= 0.5f; a1 *= 0.5f; a2 *= 0.5f; a3 *= 0.5f;

    f32x4* dst = (f32x4*)(esym + (size_t)k * EDGE_DIM);
    __builtin_nontemporal_store(a0, dst + 0);
    __builtin_nontemporal_store(a1, dst + 1);
    __builtin_nontemporal_store(a2, dst + 2);
    __builtin_nontemporal_store(a3, dst + 3);
}

// ---------------------------------------------------------------------------
// Hash fallback (used only if ws_size too small for direct table)
// slot u64 = ((key+1)<<18) | edge_id, winner = max edge_id. Empty = 0.
// ---------------------------------------------------------------------------
__global__ __launch_bounds__(256) void k_insert_h(const int* __restrict__ eidx,
                                                  unsigned long long* __restrict__ tab) {
    const int k = blockIdx.x * blockDim.x + threadIdx.x;
    const unsigned j = (unsigned)eidx[k];
    const unsigned i = (unsigned)eidx[E_EDGES + k];
    const unsigned key = (j << 12) | i;
    const unsigned long long mine =
        ((unsigned long long)(key + 1u) << 18) | (unsigned)k;
    unsigned h = (key * 2654435761u) >> (32 - TBITS);
    while (true) {
        unsigned long long cur = tab[h];
        if (cur == 0ULL) {
            const unsigned long long old = atomicCAS(&tab[h], 0ULL, mine);
            if (old == 0ULL) return;
            cur = old;
        }
        if ((unsigned)(cur >> 18) == key + 1u) {
            atomicMax(&tab[h], mine);
            return;
        }
        h = (h + 1u) & TMASK;
    }
}

__device__ __forceinline__ int hlookup(const unsigned long long* __restrict__ tab,
                                       unsigned key) {
    unsigned h = (key * 2654435761u) >> (32 - TBITS);
    while (true) {
        const unsigned long long cur = tab[h];
        if (cur == 0ULL) return -1;
        if ((unsigned)(cur >> 18) == key + 1u) return (int)(cur & 0x3FFFFu);
        h = (h + 1u) & TMASK;
    }
}

__global__ __launch_bounds__(256) void k_esym_h(const int* __restrict__ eidx,
                                                const float* __restrict__ e,
                                                const unsigned long long* __restrict__ tab,
                                                float* __restrict__ esym) {
    const int k = blockIdx.x * blockDim.x + threadIdx.x;
    const unsigned j = (unsigned)eidx[k];
    const unsigned i = (unsigned)eidx[E_EDGES + k];

    const f32x4* eo = (const f32x4*)(e + (size_t)k * EDGE_DIM);
    f32x4 a0 = eo[0], a1 = eo[1], a2 = eo[2], a3 = eo[3];

    const int wf = hlookup(tab, (j << 12) | i);
    const int wr = hlookup(tab, (i << 12) | j);

    if (wf != k) {
        const f32x4* ef = (const f32x4*)(e + (size_t)wf * EDGE_DIM);
        a0 = ef[0]; a1 = ef[1]; a2 = ef[2]; a3 = ef[3];
    }
    if (wr >= 0) {
        const f32x4* er = (const f32x4*)(e + (size_t)wr * EDGE_DIM);
        a0 += er[0]; a1 += er[1]; a2 += er[2]; a3 += er[3];
    }
    a0 *= 0.5f; a1 *= 0.5f; a2 *= 0.5f; a3 *= 0.5f;

    f32x4* dst = (f32x4*)(esym + (size_t)k * EDGE_DIM);
    __builtin_nontemporal_store(a0, dst + 0);
    __builtin_nontemporal_store(a1, dst + 1);
    __builtin_nontemporal_store(a2, dst + 2);
    __builtin_nontemporal_store(a3, dst + 3);
}

// ---------------------------------------------------------------------------
// K4b: streaming edge kernel (unchanged from R3 — VALU-bound at 72%).
// ---------------------------------------------------------------------------
#define EPW 16   // edges per wave; grid fixed at 4096 blocks x 256

__global__ __launch_bounds__(256, 4) void k_edges2(const int* __restrict__ eidx,
                                                   const float* __restrict__ esym,
                                                   const float* __restrict__ s_act,
                                                   const float* __restrict__ Wb,
                                                   const float* __restrict__ bb,
                                                   const float* __restrict__ Wbs,
                                                   const float* __restrict__ bbs,
                                                   float* __restrict__ out) {
    const int lane  = threadIdx.x & 63;
    const int wave  = (blockIdx.x * blockDim.x + threadIdx.x) >> 6;
    const int base  = __builtin_amdgcn_readfirstlane(wave * EPW);
    const int cbase = lane * 4;

    float wbond[4][16];
#pragma unroll
    for (int r = 0; r < 4; ++r) {
        const float4* wp = (const float4*)(Wb + (cbase + r) * EDGE_DIM);
#pragma unroll
        for (int d4 = 0; d4 < 4; ++d4) {
            const float4 v = wp[d4];
            wbond[r][d4 * 4 + 0] = v.x; wbond[r][d4 * 4 + 1] = v.y;
            wbond[r][d4 * 4 + 2] = v.z; wbond[r][d4 * 4 + 3] = v.w;
        }
    }
    float wbs[NBT][4];
#pragma unroll
    for (int q = 0; q < NBT; ++q) {
        const float4 v = *(const float4*)(Wbs + q * IN_DIM + cbase);
        wbs[q][0] = v.x; wbs[q][1] = v.y; wbs[q][2] = v.z; wbs[q][3] = v.w;
    }
    float bias[4];
    {
        const float4 v = *(const float4*)(bb + cbase);
        bias[0] = v.x; bias[1] = v.y; bias[2] = v.z; bias[3] = v.w;
    }
    float bb5[NBT];
#pragma unroll
    for (int q = 0; q < NBT; ++q) bb5[q] = bbs[q];

#pragma unroll 2
    for (int t = 0; t < EPW; t += 2) {
        const int k0 = base + t;
        const int k1 = base + t + 1;

        const int j0 = eidx[k0];
        const int i0 = eidx[E_EDGES + k0];
        const int j1 = eidx[k1];
        const int i1 = eidx[E_EDGES + k1];

        float es0[16], es1[16];
#pragma unroll
        for (int d = 0; d < 16; ++d) es0[d] = esym[(size_t)k0 * EDGE_DIM + d];
#pragma unroll
        for (int d = 0; d < 16; ++d) es1[d] = esym[(size_t)k1 * EDGE_DIM + d];

        const float4 si0 = *(const float4*)(s_act + (size_t)i0 * IN_DIM + cbase);
        const float4 sj0 = *(const float4*)(s_act + (size_t)j0 * IN_DIM + cbase);
        const float4 si1 = *(const float4*)(s_act + (size_t)i1 * IN_DIM + cbase);
        const float4 sj1 = *(const float4*)(s_act + (size_t)j1 * IN_DIM + cbase);

        const float s0f[4] = {si0.x + sj0.x, si0.y + sj0.y, si0.z + sj0.z, si0.w + sj0.w};
        const float s1f[4] = {si1.x + sj1.x, si1.y + sj1.y, si1.z + sj1.z, si1.w + sj1.w};

        float f0[4], f1[4];
#pragma unroll
        for (int r = 0; r < 4; ++r) {
            float t0 = bias[r] + s0f[r];
            float t1 = bias[r] + s1f[r];
#pragma unroll
            for (int d = 0; d < 16; ++d) {
                t0 += es0[d] * wbond[r][d];
                t1 += es1[d] * wbond[r][d];
            }
            f0[r] = silu_f(t0);
            f1[r] = silu_f(t1);
        }

        float p0[NBT], p1[NBT];
#pragma unroll
        for (int q = 0; q < NBT; ++q) {
            p0[q] = f0[0] * wbs[q][0] + f0[1] * wbs[q][1] +
                    f0[2] * wbs[q][2] + f0[3] * wbs[q][3];
            p1[q] = f1[0] * wbs[q][0] + f1[1] * wbs[q][1] +
                    f1[2] * wbs[q][2] + f1[3] * wbs[q][3];
        }
#pragma unroll
        for (int off = 32; off > 0; off >>= 1) {
#pragma unroll
            for (int q = 0; q < NBT; ++q) {
                p0[q] += __shfl_xor(p0[q], off, 64);
                p1[q] += __shfl_xor(p1[q], off, 64);
            }
        }

        float v0 = p0[0] + bb5[0];
        v0 = (lane == 1) ? p0[1] + bb5[1] : v0;
        v0 = (lane == 2) ? p0[2] + bb5[2] : v0;
        v0 = (lane == 3) ? p0[3] + bb5[3] : v0;
        v0 = (lane == 4) ? p0[4] + bb5[4] : v0;
        float v1 = p1[0] + bb5[0];
        v1 = (lane == 1) ? p1[1] + bb5[1] : v1;
        v1 = (lane == 2) ? p1[2] + bb5[2] : v1;
        v1 = (lane == 3) ? p1[3] + bb5[3] : v1;
        v1 = (lane == 4) ? p1[4] + bb5[4] : v1;
        if (lane < 5) {
            __builtin_nontemporal_store(v0, &out[BONDS_OFF + (size_t)k0 * NBT + lane]);
            __builtin_nontemporal_store(v1, &out[BONDS_OFF + (size_t)k1 * NBT + lane]);
        }
    }
}

// ---------------------------------------------------------------------------
extern "C" void kernel_launch(void* const* d_in, const int* in_sizes, int n_in,
                              void* d_out, int out_size, void* d_ws, size_t ws_size,
                              hipStream_t stream) {
    const float* s   = (const float*)d_in[0];
    const float* e   = (const float*)d_in[1];
    const int*   eix = (const int*)d_in[3];
    const float* Wsh = (const float*)d_in[4];
    const float* bsh = (const float*)d_in[5];
    const float* Wb  = (const float*)d_in[6];
    const float* bbo = (const float*)d_in[7];
    const float* Wbs = (const float*)d_in[8];
    const float* bbs = (const float*)d_in[9];
    const float* Wa  = (const float*)d_in[10];
    const float* ba  = (const float*)d_in[11];
    float* out = (float*)d_out;

    char* ws = (char*)d_ws;
    float* s_act = (float*)ws;                  // 4 MB @ 0
    float* esym  = (float*)(ws + (4u << 20));   // 16 MB @ 4 MB
    char*  tmem  = ws + (20u << 20);            // table @ 20 MB

    const bool use_direct = (ws_size >= ((size_t)84 << 20));

    if (use_direct) {
        unsigned* T = (unsigned*)tmem;          // 64 MB
        (void)hipMemsetAsync(T, 0x00, (size_t)DKEYS * sizeof(unsigned), stream);
        k_insert_d<<<E_EDGES / 256, 256, 0, stream>>>(eix, T);
        k12<<<N_NODES / 8, 256, 0, stream>>>(s, Wsh, bsh, Wa, ba, s_act, out);
        k_esym_d<<<E_EDGES / 256, 256, 0, stream>>>(eix, e, T, esym);
    } else {
        unsigned long long* tab = (unsigned long long*)tmem;  // 8 MB
        (void)hipMemsetAsync(tab, 0x00, TSIZE * sizeof(unsigned long long), stream);
        k_insert_h<<<E_EDGES / 256, 256, 0, stream>>>(eix, tab);
        k12<<<N_NODES / 8, 256, 0, stream>>>(s, Wsh, bsh, Wa, ba, s_act, out);
        k_esym_h<<<E_EDGES / 256, 256, 0, stream>>>(eix, e, tab, esym);
    }
    k_edges2<<<4096, 256, 0, stream>>>(eix, esym, s_act, Wb, bbo, Wbs, bbs, out);
}

// Round 6
// 265.707 us; speedup vs baseline: 1.8246x; 1.0626x over previous
//
#include <hip/hip_runtime.h>
#include <hip/hip_bf16.h>

#define N_NODES   4096
#define E_EDGES   262144
#define IN_DIM    256
#define EDGE_DIM  16
#define NAF       16
#define LATENT    128
#define NBT       5

#define LATENT_OFF 0
#define ATOMS_OFF  (N_NODES * LATENT)                 // 524288
#define BONDS_OFF  (ATOMS_OFF + N_NODES * NAF)        // 589824

// hash fallback
#define TBITS 20
#define TSIZE (1u << TBITS)
#define TMASK (TSIZE - 1u)
// direct table: 2^24 u32 entries = 64 MB
#define DKEYS (1u << 24)

typedef float  f32x4  __attribute__((ext_vector_type(4)));
typedef float  f32x4v __attribute__((ext_vector_type(4)));
typedef short  bf16x8 __attribute__((ext_vector_type(8)));
typedef unsigned u32x4 __attribute__((ext_vector_type(4)));

__device__ __forceinline__ float silu_f(float x) {
    return x / (1.0f + __expf(-x));
}

__device__ __forceinline__ unsigned pack_bf16x2(float lo, float hi) {
    __hip_bfloat162 h = __float22bfloat162_rn(make_float2(lo, hi));
    union { __hip_bfloat162 h; unsigned u; } c;
    c.h = h;
    return c.u;
}

// ---------------------------------------------------------------------------
// K12: s_act = silu(s @ W_shared^T + b);  atoms_out = s_act @ W_atoms^T + b
// (unchanged — passed R4)
// ---------------------------------------------------------------------------
__global__ __launch_bounds__(256) void k12(const float* __restrict__ s,
                                           const float* __restrict__ Wsh,
                                           const float* __restrict__ bsh,
                                           const float* __restrict__ Wa,
                                           const float* __restrict__ ba,
                                           float* __restrict__ s_act,
                                           float* __restrict__ out) {
    __shared__ float sl[8][32];
    __shared__ float st[8][IN_DIM];
    const int c  = threadIdx.x;
    const int r0 = blockIdx.x * 8;

    float acc[8];
    const float bias = bsh[c];
#pragma unroll
    for (int r = 0; r < 8; ++r) acc[r] = bias;

    for (int k0 = 0; k0 < IN_DIM; k0 += 32) {
        sl[c >> 5][c & 31] = s[(r0 + (c >> 5)) * IN_DIM + k0 + (c & 31)];
        __syncthreads();

        float4 w4[8];
        const float4* wp = (const float4*)(Wsh + c * IN_DIM + k0);
#pragma unroll
        for (int q = 0; q < 8; ++q) w4[q] = wp[q];
        const float* wf = (const float*)w4;
#pragma unroll
        for (int r = 0; r < 8; ++r) {
            const float4* srow = (const float4*)sl[r];
            float a = acc[r];
#pragma unroll
            for (int q = 0; q < 8; ++q) {
                const float4 sv = srow[q];
                a += sv.x * wf[q * 4 + 0];
                a += sv.y * wf[q * 4 + 1];
                a += sv.z * wf[q * 4 + 2];
                a += sv.w * wf[q * 4 + 3];
            }
            acc[r] = a;
        }
        __syncthreads();
    }
#pragma unroll
    for (int r = 0; r < 8; ++r) {
        const float v = silu_f(acc[r]);
        s_act[(r0 + r) * IN_DIM + c] = v;
        st[r][c] = v;
    }
    __syncthreads();

    const bool active = (c < (NAF + LATENT));
    float acc2[8];
    const float bias2 = active ? ba[c] : 0.0f;
#pragma unroll
    for (int r = 0; r < 8; ++r) acc2[r] = bias2;

    if (active) {
        for (int k0 = 0; k0 < IN_DIM; k0 += 32) {
            float4 w4[8];
            const float4* wp = (const float4*)(Wa + c * IN_DIM + k0);
#pragma unroll
            for (int q = 0; q < 8; ++q) w4[q] = wp[q];
            const float* wf = (const float*)w4;
#pragma unroll
            for (int r = 0; r < 8; ++r) {
                const float4* srow = (const float4*)(st[r] + k0);
                float a = acc2[r];
#pragma unroll
                for (int q = 0; q < 8; ++q) {
                    const float4 sv = srow[q];
                    a += sv.x * wf[q * 4 + 0];
                    a += sv.y * wf[q * 4 + 1];
                    a += sv.z * wf[q * 4 + 2];
                    a += sv.w * wf[q * 4 + 3];
                }
                acc2[r] = a;
            }
        }
#pragma unroll
        for (int r = 0; r < 8; ++r) {
            const int row = r0 + r;
            if (c < NAF) out[ATOMS_OFF + row * NAF + c] = acc2[r];
            else         out[LATENT_OFF + row * LATENT + (c - NAF)] = acc2[r];
        }
    }
}

// ---------------------------------------------------------------------------
// Direct table: T[key] = max(edge_id+1), key = (j<<12)|i. Empty = 0.
// ---------------------------------------------------------------------------
__global__ __launch_bounds__(256) void k_insert_d(const int* __restrict__ eidx,
                                                  unsigned* __restrict__ T) {
    const int k = blockIdx.x * blockDim.x + threadIdx.x;
    const unsigned j = (unsigned)eidx[k];
    const unsigned i = (unsigned)eidx[E_EDGES + k];
    atomicMax(&T[(j << 12) | i], (unsigned)(k + 1));
}

__device__ __forceinline__ void esym_store_bf16(unsigned short* dst, int k,
                                                f32x4 a0, f32x4 a1, f32x4 a2, f32x4 a3) {
    u32x4 w0, w1;
    w0.x = pack_bf16x2(a0.x, a0.y); w0.y = pack_bf16x2(a0.z, a0.w);
    w0.z = pack_bf16x2(a1.x, a1.y); w0.w = pack_bf16x2(a1.z, a1.w);
    w1.x = pack_bf16x2(a2.x, a2.y); w1.y = pack_bf16x2(a2.z, a2.w);
    w1.z = pack_bf16x2(a3.x, a3.y); w1.w = pack_bf16x2(a3.z, a3.w);
    u32x4* p = (u32x4*)(dst + (size_t)k * EDGE_DIM);
    __builtin_nontemporal_store(w0, p + 0);
    __builtin_nontemporal_store(w1, p + 1);
}

__global__ __launch_bounds__(256) void k_esym_d(const int* __restrict__ eidx,
                                                const float* __restrict__ e,
                                                const unsigned* __restrict__ T,
                                                unsigned short* __restrict__ esym) {
    const int k = blockIdx.x * blockDim.x + threadIdx.x;
    const unsigned j = (unsigned)eidx[k];
    const unsigned i = (unsigned)eidx[E_EDGES + k];

    const f32x4* eo = (const f32x4*)(e + (size_t)k * EDGE_DIM);
    f32x4 a0 = eo[0], a1 = eo[1], a2 = eo[2], a3 = eo[3];

    const unsigned wf = T[(j << 12) | i];   // >= 1 always
    const unsigned wr = T[(i << 12) | j];   // 0 if absent

    if ((int)(wf - 1u) != k) {
        const f32x4* ef = (const f32x4*)(e + (size_t)(wf - 1u) * EDGE_DIM);
        a0 = ef[0]; a1 = ef[1]; a2 = ef[2]; a3 = ef[3];
    }
    if (wr != 0u) {
        const f32x4* er = (const f32x4*)(e + (size_t)(wr - 1u) * EDGE_DIM);
        a0 += er[0]; a1 += er[1]; a2 += er[2]; a3 += er[3];
    }
    a0 *= 0.5f; a1 *= 0.5f; a2 *= 0.5f; a3 *= 0.5f;
    esym_store_bf16(esym, k, a0, a1, a2, a3);
}

// ---------------------------------------------------------------------------
// Hash fallback
// ---------------------------------------------------------------------------
__global__ __launch_bounds__(256) void k_insert_h(const int* __restrict__ eidx,
                                                  unsigned long long* __restrict__ tab) {
    const int k = blockIdx.x * blockDim.x + threadIdx.x;
    const unsigned j = (unsigned)eidx[k];
    const unsigned i = (unsigned)eidx[E_EDGES + k];
    const unsigned key = (j << 12) | i;
    const unsigned long long mine =
        ((unsigned long long)(key + 1u) << 18) | (unsigned)k;
    unsigned h = (key * 2654435761u) >> (32 - TBITS);
    while (true) {
        unsigned long long cur = tab[h];
        if (cur == 0ULL) {
            const unsigned long long old = atomicCAS(&tab[h], 0ULL, mine);
            if (old == 0ULL) return;
            cur = old;
        }
        if ((unsigned)(cur >> 18) == key + 1u) {
            atomicMax(&tab[h], mine);
            return;
        }
        h = (h + 1u) & TMASK;
    }
}

__device__ __forceinline__ int hlookup(const unsigned long long* __restrict__ tab,
                                       unsigned key) {
    unsigned h = (key * 2654435761u) >> (32 - TBITS);
    while (true) {
        const unsigned long long cur = tab[h];
        if (cur == 0ULL) return -1;
        if ((unsigned)(cur >> 18) == key + 1u) return (int)(cur & 0x3FFFFu);
        h = (h + 1u) & TMASK;
    }
}

__global__ __launch_bounds__(256) void k_esym_h(const int* __restrict__ eidx,
                                                const float* __restrict__ e,
                                                const unsigned long long* __restrict__ tab,
                                                unsigned short* __restrict__ esym) {
    const int k = blockIdx.x * blockDim.x + threadIdx.x;
    const unsigned j = (unsigned)eidx[k];
    const unsigned i = (unsigned)eidx[E_EDGES + k];

    const f32x4* eo = (const f32x4*)(e + (size_t)k * EDGE_DIM);
    f32x4 a0 = eo[0], a1 = eo[1], a2 = eo[2], a3 = eo[3];

    const int wf = hlookup(tab, (j << 12) | i);
    const int wr = hlookup(tab, (i << 12) | j);

    if (wf != k) {
        const f32x4* ef = (const f32x4*)(e + (size_t)wf * EDGE_DIM);
        a0 = ef[0]; a1 = ef[1]; a2 = ef[2]; a3 = ef[3];
    }
    if (wr >= 0) {
        const f32x4* er = (const f32x4*)(e + (size_t)wr * EDGE_DIM);
        a0 += er[0]; a1 += er[1]; a2 += er[2]; a3 += er[3];
    }
    a0 *= 0.5f; a1 *= 0.5f; a2 *= 0.5f; a3 *= 0.5f;
    esym_store_bf16(esym, k, a0, a1, a2, a3);
}

// ---------------------------------------------------------------------------
// K4: MFMA edge kernel. Per wave-iteration: 16 edges.
// ALL LDS accesses are scalar `unsigned` (TBAA-consistent) + asm memory
// barriers at phase boundaries — R5's NaN was mixed u32-store/u16-load
// reordering.
//   ssum  : u32[e][130]   e<16, word w holds channels 2w,2w+1 (bf16 pair)
//   fT    : u32[ch][9]    ch<256, word 2q+t holds edges 4q+2t,4q+2t+1
// MFMA layouts: A[m=lane&15][k=8*(lane>>4)+j]; B[k=8*(lane>>4)+j][n=lane&15];
// C/D col=lane&15, row=4*(lane>>4)+reg  (guide §3, m89/m120-verified).
// Grid: 1024 blocks x 256 -> 4096 waves x 4 iters x 16 edges = 262144.
// ---------------------------------------------------------------------------
#define LDSU 2304   // u32 per wave: ssum needs 16*130=2080, fT needs 256*9=2304

__global__ __launch_bounds__(256) void k_edges_mfma(const int* __restrict__ eidx,
                                                    const unsigned short* __restrict__ esym,
                                                    const float* __restrict__ s_act,
                                                    const float* __restrict__ Wb,
                                                    const float* __restrict__ bb,
                                                    const float* __restrict__ Wbs,
                                                    const float* __restrict__ bbs,
                                                    float* __restrict__ out) {
    __shared__ unsigned lds_all[4][LDSU];
    const int tid  = threadIdx.x;
    const int lane = tid & 63;
    const int wv   = tid >> 6;
    const int m    = lane & 15;   // tile row/col index
    const int q    = lane >> 4;   // quad
    const bool modd = (m & 1);
    unsigned* myl = lds_all[wv];

    const int wbase = __builtin_amdgcn_readfirstlane((blockIdx.x * 4 + wv) * 64);

    // ---- B1 frags: B1[g][k=8q+j][n=m] = Wb[16g+m][8q+j], quads>=2 zero (K pad)
    bf16x8 B1[16];
#pragma unroll
    for (int g = 0; g < 16; ++g) {
        union { bf16x8 v; unsigned u[4]; } r;
        r.u[0] = r.u[1] = r.u[2] = r.u[3] = 0u;
        if (q < 2) {
            const float* wr_ = Wb + (16 * g + m) * EDGE_DIM + 8 * q;
            const float4 w0 = *(const float4*)(wr_ + 0);
            const float4 w1 = *(const float4*)(wr_ + 4);
            r.u[0] = pack_bf16x2(w0.x, w0.y);
            r.u[1] = pack_bf16x2(w0.z, w0.w);
            r.u[2] = pack_bf16x2(w1.x, w1.y);
            r.u[3] = pack_bf16x2(w1.z, w1.w);
        }
        B1[g] = r.v;
    }
    // ---- B2 frags: B2[c][k=32c+8q+j][n=m] = Wbs[m][32c+8q+j], n>=5 zero
    bf16x8 B2[8];
#pragma unroll
    for (int c = 0; c < 8; ++c) {
        union { bf16x8 v; unsigned u[4]; } r;
        r.u[0] = r.u[1] = r.u[2] = r.u[3] = 0u;
        if (m < NBT) {
            const float* wr_ = Wbs + m * IN_DIM + 32 * c + 8 * q;
            const float4 w0 = *(const float4*)(wr_ + 0);
            const float4 w1 = *(const float4*)(wr_ + 4);
            r.u[0] = pack_bf16x2(w0.x, w0.y);
            r.u[1] = pack_bf16x2(w0.z, w0.w);
            r.u[2] = pack_bf16x2(w1.x, w1.y);
            r.u[3] = pack_bf16x2(w1.z, w1.w);
        }
        B2[c] = r.v;
    }
    const float4 bias4 = *(const float4*)(bb + 4 * lane);
    const float  bbs_m = (m < NBT) ? bbs[m] : 0.0f;

#pragma unroll 1
    for (int it = 0; it < 4; ++it) {
        const int k0 = wbase + 16 * it;

        // ---- phase 0: ssum[e][*] = bf16(s_act[i]+s_act[j]+bb)
#pragma unroll
        for (int e = 0; e < 16; ++e) {
            const int j_e = eidx[k0 + e];
            const int i_e = eidx[E_EDGES + k0 + e];
            const float4 a = *(const float4*)(s_act + (size_t)i_e * IN_DIM + 4 * lane);
            const float4 b = *(const float4*)(s_act + (size_t)j_e * IN_DIM + 4 * lane);
            const float x0 = a.x + b.x + bias4.x;
            const float x1 = a.y + b.y + bias4.y;
            const float x2 = a.z + b.z + bias4.z;
            const float x3 = a.w + b.w + bias4.w;
            myl[e * 130 + 2 * lane]     = pack_bf16x2(x0, x1);
            myl[e * 130 + 2 * lane + 1] = pack_bf16x2(x2, x3);
        }
        __asm__ __volatile__("" ::: "memory");

        // ---- A1 frag: esym rows k0..k0+15, K=16 live in quads 0,1
        bf16x8 A1 = {0, 0, 0, 0, 0, 0, 0, 0};
        if (lane < 32)
            A1 = *(const bf16x8*)(esym + (size_t)(k0 + m) * EDGE_DIM + 8 * q);

        // ---- GEMM1: t = A1*B1 + ssum (C-init from LDS)
        f32x4v P[16];
#pragma unroll
        for (int g = 0; g < 16; ++g) {
            union { f32x4v v; unsigned u[4]; } cc;
#pragma unroll
            for (int r = 0; r < 4; ++r) {
                const unsigned u = myl[(4 * q + r) * 130 + 8 * g + (m >> 1)];
                cc.u[r] = modd ? (u & 0xFFFF0000u) : (u << 16);
            }
            P[g] = __builtin_amdgcn_mfma_f32_16x16x32_bf16(A1, B1[g], cc.v, 0, 0, 0);
        }
        __asm__ __volatile__("" ::: "memory");

        // ---- silu + bf16 + transpose to fT[ch][9]
#pragma unroll
        for (int g = 0; g < 16; ++g) {
            const float f0 = silu_f(P[g][0]);
            const float f1 = silu_f(P[g][1]);
            const float f2 = silu_f(P[g][2]);
            const float f3 = silu_f(P[g][3]);
            const int col = 16 * g + m;
            myl[col * 9 + 2 * q]     = pack_bf16x2(f0, f1);
            myl[col * 9 + 2 * q + 1] = pack_bf16x2(f2, f3);
        }
        __asm__ __volatile__("" ::: "memory");

        // ---- GEMM2: bonds = fT * Wbs^T + bbs, K=256 in 8 chunks of 32
        union { f32x4v v; float f[4]; } C2;
#pragma unroll
        for (int r = 0; r < 4; ++r) C2.f[r] = bbs_m;
#pragma unroll
        for (int c = 0; c < 8; ++c) {
            union { bf16x8 v; unsigned u[4]; } a2;
#pragma unroll
            for (int t = 0; t < 4; ++t) {
                const unsigned u0 = myl[(32 * c + 8 * q + 2 * t)     * 9 + (m >> 1)];
                const unsigned u1 = myl[(32 * c + 8 * q + 2 * t + 1) * 9 + (m >> 1)];
                const unsigned lo = modd ? (u0 >> 16)        : (u0 & 0xFFFFu);
                const unsigned hi = modd ? (u1 & 0xFFFF0000u) : (u1 << 16);
                a2.u[t] = lo | hi;
            }
            C2.v = __builtin_amdgcn_mfma_f32_16x16x32_bf16(a2.v, B2[c], C2.v, 0, 0, 0);
        }

        // ---- store: lane holds bond-type col m, edges 4q+r
        if (m < NBT) {
#pragma unroll
            for (int r = 0; r < 4; ++r) {
                const int e = k0 + 4 * q + r;
                __builtin_nontemporal_store(C2.f[r], &out[BONDS_OFF + (size_t)e * NBT + m]);
            }
        }
        __asm__ __volatile__("" ::: "memory");
    }
}

// ---------------------------------------------------------------------------
extern "C" void kernel_launch(void* const* d_in, const int* in_sizes, int n_in,
                              void* d_out, int out_size, void* d_ws, size_t ws_size,
                              hipStream_t stream) {
    const float* s   = (const float*)d_in[0];
    const float* e   = (const float*)d_in[1];
    const int*   eix = (const int*)d_in[3];
    const float* Wsh = (const float*)d_in[4];
    const float* bsh = (const float*)d_in[5];
    const float* Wb  = (const float*)d_in[6];
    const float* bbo = (const float*)d_in[7];
    const float* Wbs = (const float*)d_in[8];
    const float* bbs = (const float*)d_in[9];
    const float* Wa  = (const float*)d_in[10];
    const float* ba  = (const float*)d_in[11];
    float* out = (float*)d_out;

    char* ws = (char*)d_ws;
    float*          s_act = (float*)ws;                          // 4 MB @ 0
    unsigned short* esym  = (unsigned short*)(ws + (4u << 20));  // 8 MB @ 4 MB
    char*           tmem  = ws + (12u << 20);                    // table @ 12 MB

    const bool use_direct = (ws_size >= ((size_t)80 << 20));

    if (use_direct) {
        unsigned* T = (unsigned*)tmem;                           // 64 MB
        (void)hipMemsetAsync(T, 0x00, (size_t)DKEYS * sizeof(unsigned), stream);
        k_insert_d<<<E_EDGES / 256, 256, 0, stream>>>(eix, T);
        k12<<<N_NODES / 8, 256, 0, stream>>>(s, Wsh, bsh, Wa, ba, s_act, out);
        k_esym_d<<<E_EDGES / 256, 256, 0, stream>>>(eix, e, T, esym);
    } else {
        unsigned long long* tab = (unsigned long long*)tmem;     // 8 MB
        (void)hipMemsetAsync(tab, 0x00, TSIZE * sizeof(unsigned long long), stream);
        k_insert_h<<<E_EDGES / 256, 256, 0, stream>>>(eix, tab);
        k12<<<N_NODES / 8, 256, 0, stream>>>(s, Wsh, bsh, Wa, ba, s_act, out);
        k_esym_h<<<E_EDGES / 256, 256, 0, stream>>>(eix, e, tab, esym);
    }
    k_edges_mfma<<<1024, 256, 0, stream>>>(eix, esym, s_act, Wb, bbo, Wbs, bbs, out);
}

// Round 7
// 250.068 us; speedup vs baseline: 1.9387x; 1.0625x over previous
//
#include <hip/hip_runtime.h>
#include <hip/hip_bf16.h>

#define N_NODES   4096
#define E_EDGES   262144
#define IN_DIM    256
#define EDGE_DIM  16
#define NAF       16
#define LATENT    128
#define NBT       5

#define LATENT_OFF 0
#define ATOMS_OFF  (N_NODES * LATENT)                 // 524288
#define BONDS_OFF  (ATOMS_OFF + N_NODES * NAF)        // 589824

// hash fallback
#define TBITS 20
#define TSIZE (1u << TBITS)
#define TMASK (TSIZE - 1u)
// direct table: 2^24 u32 entries = 64 MB
#define DKEYS (1u << 24)

typedef float  f32x4  __attribute__((ext_vector_type(4)));
typedef float  f32x4v __attribute__((ext_vector_type(4)));
typedef short  bf16x4 __attribute__((ext_vector_type(4)));
typedef short  bf16x8 __attribute__((ext_vector_type(8)));
typedef unsigned u32x4 __attribute__((ext_vector_type(4)));

__device__ __forceinline__ float silu_f(float x) {
    return x / (1.0f + __expf(-x));
}

__device__ __forceinline__ unsigned pack_bf16x2(float lo, float hi) {
    __hip_bfloat162 h = __float22bfloat162_rn(make_float2(lo, hi));
    union { __hip_bfloat162 h; unsigned u; } c;
    c.h = h;
    return c.u;
}

// ---------------------------------------------------------------------------
// K12: s_act = silu(s @ W_shared^T + b);  atoms_out = s_act @ W_atoms^T + b
// (unchanged — passed R4/R6)
// ---------------------------------------------------------------------------
__global__ __launch_bounds__(256) void k12(const float* __restrict__ s,
                                           const float* __restrict__ Wsh,
                                           const float* __restrict__ bsh,
                                           const float* __restrict__ Wa,
                                           const float* __restrict__ ba,
                                           float* __restrict__ s_act,
                                           float* __restrict__ out) {
    __shared__ float sl[8][32];
    __shared__ float st[8][IN_DIM];
    const int c  = threadIdx.x;
    const int r0 = blockIdx.x * 8;

    float acc[8];
    const float bias = bsh[c];
#pragma unroll
    for (int r = 0; r < 8; ++r) acc[r] = bias;

    for (int k0 = 0; k0 < IN_DIM; k0 += 32) {
        sl[c >> 5][c & 31] = s[(r0 + (c >> 5)) * IN_DIM + k0 + (c & 31)];
        __syncthreads();

        float4 w4[8];
        const float4* wp = (const float4*)(Wsh + c * IN_DIM + k0);
#pragma unroll
        for (int q = 0; q < 8; ++q) w4[q] = wp[q];
        const float* wf = (const float*)w4;
#pragma unroll
        for (int r = 0; r < 8; ++r) {
            const float4* srow = (const float4*)sl[r];
            float a = acc[r];
#pragma unroll
            for (int q = 0; q < 8; ++q) {
                const float4 sv = srow[q];
                a += sv.x * wf[q * 4 + 0];
                a += sv.y * wf[q * 4 + 1];
                a += sv.z * wf[q * 4 + 2];
                a += sv.w * wf[q * 4 + 3];
            }
            acc[r] = a;
        }
        __syncthreads();
    }
#pragma unroll
    for (int r = 0; r < 8; ++r) {
        const float v = silu_f(acc[r]);
        s_act[(r0 + r) * IN_DIM + c] = v;
        st[r][c] = v;
    }
    __syncthreads();

    const bool active = (c < (NAF + LATENT));
    float acc2[8];
    const float bias2 = active ? ba[c] : 0.0f;
#pragma unroll
    for (int r = 0; r < 8; ++r) acc2[r] = bias2;

    if (active) {
        for (int k0 = 0; k0 < IN_DIM; k0 += 32) {
            float4 w4[8];
            const float4* wp = (const float4*)(Wa + c * IN_DIM + k0);
#pragma unroll
            for (int q = 0; q < 8; ++q) w4[q] = wp[q];
            const float* wf = (const float*)w4;
#pragma unroll
            for (int r = 0; r < 8; ++r) {
                const float4* srow = (const float4*)(st[r] + k0);
                float a = acc2[r];
#pragma unroll
                for (int q = 0; q < 8; ++q) {
                    const float4 sv = srow[q];
                    a += sv.x * wf[q * 4 + 0];
                    a += sv.y * wf[q * 4 + 1];
                    a += sv.z * wf[q * 4 + 2];
                    a += sv.w * wf[q * 4 + 3];
                }
                acc2[r] = a;
            }
        }
#pragma unroll
        for (int r = 0; r < 8; ++r) {
            const int row = r0 + r;
            if (c < NAF) out[ATOMS_OFF + row * NAF + c] = acc2[r];
            else         out[LATENT_OFF + row * LATENT + (c - NAF)] = acc2[r];
        }
    }
}

// ---------------------------------------------------------------------------
// Direct table: T[key] = max(edge_id+1), key = (j<<12)|i. Empty = 0.
// ---------------------------------------------------------------------------
__global__ __launch_bounds__(256) void k_insert_d(const int* __restrict__ eidx,
                                                  unsigned* __restrict__ T) {
    const int k = blockIdx.x * blockDim.x + threadIdx.x;
    const unsigned j = (unsigned)eidx[k];
    const unsigned i = (unsigned)eidx[E_EDGES + k];
    atomicMax(&T[(j << 12) | i], (unsigned)(k + 1));
}

__device__ __forceinline__ void esym_store_bf16(unsigned short* dst, int k,
                                                f32x4 a0, f32x4 a1, f32x4 a2, f32x4 a3) {
    u32x4 w0, w1;
    w0.x = pack_bf16x2(a0.x, a0.y); w0.y = pack_bf16x2(a0.z, a0.w);
    w0.z = pack_bf16x2(a1.x, a1.y); w0.w = pack_bf16x2(a1.z, a1.w);
    w1.x = pack_bf16x2(a2.x, a2.y); w1.y = pack_bf16x2(a2.z, a2.w);
    w1.z = pack_bf16x2(a3.x, a3.y); w1.w = pack_bf16x2(a3.z, a3.w);
    u32x4* p = (u32x4*)(dst + (size_t)k * EDGE_DIM);
    __builtin_nontemporal_store(w0, p + 0);
    __builtin_nontemporal_store(w1, p + 1);
}

__global__ __launch_bounds__(256) void k_esym_d(const int* __restrict__ eidx,
                                                const float* __restrict__ e,
                                                const unsigned* __restrict__ T,
                                                unsigned short* __restrict__ esym) {
    const int k = blockIdx.x * blockDim.x + threadIdx.x;
    const unsigned j = (unsigned)eidx[k];
    const unsigned i = (unsigned)eidx[E_EDGES + k];

    const f32x4* eo = (const f32x4*)(e + (size_t)k * EDGE_DIM);
    f32x4 a0 = eo[0], a1 = eo[1], a2 = eo[2], a3 = eo[3];

    const unsigned wf = T[(j << 12) | i];   // >= 1 always
    const unsigned wr = T[(i << 12) | j];   // 0 if absent

    if ((int)(wf - 1u) != k) {
        const f32x4* ef = (const f32x4*)(e + (size_t)(wf - 1u) * EDGE_DIM);
        a0 = ef[0]; a1 = ef[1]; a2 = ef[2]; a3 = ef[3];
    }
    if (wr != 0u) {
        const f32x4* er = (const f32x4*)(e + (size_t)(wr - 1u) * EDGE_DIM);
        a0 += er[0]; a1 += er[1]; a2 += er[2]; a3 += er[3];
    }
    a0 *= 0.5f; a1 *= 0.5f; a2 *= 0.5f; a3 *= 0.5f;
    esym_store_bf16(esym, k, a0, a1, a2, a3);
}

// ---------------------------------------------------------------------------
// Hash fallback
// ---------------------------------------------------------------------------
__global__ __launch_bounds__(256) void k_insert_h(const int* __restrict__ eidx,
                                                  unsigned long long* __restrict__ tab) {
    const int k = blockIdx.x * blockDim.x + threadIdx.x;
    const unsigned j = (unsigned)eidx[k];
    const unsigned i = (unsigned)eidx[E_EDGES + k];
    const unsigned key = (j << 12) | i;
    const unsigned long long mine =
        ((unsigned long long)(key + 1u) << 18) | (unsigned)k;
    unsigned h = (key * 2654435761u) >> (32 - TBITS);
    while (true) {
        unsigned long long cur = tab[h];
        if (cur == 0ULL) {
            const unsigned long long old = atomicCAS(&tab[h], 0ULL, mine);
            if (old == 0ULL) return;
            cur = old;
        }
        if ((unsigned)(cur >> 18) == key + 1u) {
            atomicMax(&tab[h], mine);
            return;
        }
        h = (h + 1u) & TMASK;
    }
}

__device__ __forceinline__ int hlookup(const unsigned long long* __restrict__ tab,
                                       unsigned key) {
    unsigned h = (key * 2654435761u) >> (32 - TBITS);
    while (true) {
        const unsigned long long cur = tab[h];
        if (cur == 0ULL) return -1;
        if ((unsigned)(cur >> 18) == key + 1u) return (int)(cur & 0x3FFFFu);
        h = (h + 1u) & TMASK;
    }
}

__global__ __launch_bounds__(256) void k_esym_h(const int* __restrict__ eidx,
                                                const float* __restrict__ e,
                                                const unsigned long long* __restrict__ tab,
                                                unsigned short* __restrict__ esym) {
    const int k = blockIdx.x * blockDim.x + threadIdx.x;
    const unsigned j = (unsigned)eidx[k];
    const unsigned i = (unsigned)eidx[E_EDGES + k];

    const f32x4* eo = (const f32x4*)(e + (size_t)k * EDGE_DIM);
    f32x4 a0 = eo[0], a1 = eo[1], a2 = eo[2], a3 = eo[3];

    const int wf = hlookup(tab, (j << 12) | i);
    const int wr = hlookup(tab, (i << 12) | j);

    if (wf != k) {
        const f32x4* ef = (const f32x4*)(e + (size_t)wf * EDGE_DIM);
        a0 = ef[0]; a1 = ef[1]; a2 = ef[2]; a3 = ef[3];
    }
    if (wr >= 0) {
        const f32x4* er = (const f32x4*)(e + (size_t)wr * EDGE_DIM);
        a0 += er[0]; a1 += er[1]; a2 += er[2]; a3 += er[3];
    }
    a0 *= 0.5f; a1 *= 0.5f; a2 *= 0.5f; a3 *= 0.5f;
    esym_store_bf16(esym, k, a0, a1, a2, a3);
}

// ---------------------------------------------------------------------------
// K4: zero-LDS MFMA edge kernel. 16 edges per wave-iteration.
// Transposed formulation: t^T = Wb @ esym^T  (+ s_i + s_j as fp32 C-init,
// + bb via a folded ones-column), then bonds^T = Wbs @ f^T with f = silu(t)
// consumed DIRECTLY from the previous D registers (quad-aligned K=16 chunks).
// K=16 chunks run on the verified 16x16x32 intrinsic by placing data in
// slots j<4 of each quad on BOTH operands (identical k-renaming => exact).
// Slot j=4: A carries bb[ch], B carries (q==0 ? 1 : 0)  -> bias folded.
// Layouts (guide §3, m89/m120-verified): A[m=lane&15][k=8q+j];
// B[k=8q+j][n=lane&15]; C/D col=lane&15 (EDGE), row=4q+r (channel/bond).
// Grid: 1024 blocks x 256 -> 4096 waves x 4 iters x 16 edges = 262144.
// ---------------------------------------------------------------------------
__global__ __launch_bounds__(256) void k_edges_mfma(const int* __restrict__ eidx,
                                                    const unsigned short* __restrict__ esym,
                                                    const float* __restrict__ s_act,
                                                    const float* __restrict__ Wb,
                                                    const float* __restrict__ bb,
                                                    const float* __restrict__ Wbs,
                                                    const float* __restrict__ bbs,
                                                    float* __restrict__ out) {
    const int lane = threadIdx.x & 63;
    const int wv   = threadIdx.x >> 6;
    const int m    = lane & 15;   // edge-within-tile (cols of D)
    const int q    = lane >> 4;   // quad (rows 4q+r of D)
    const int wbase = __builtin_amdgcn_readfirstlane((blockIdx.x * 4 + wv) * 64);

    const short one_q0 = (q == 0) ? (short)0x3F80 : (short)0;  // bf16(1.0) in quad 0

    // acc C-init from bbs (bond = 4q+r), guarded scalar loads
    f32x4v acc_init;
#pragma unroll
    for (int r = 0; r < 4; ++r) {
        const int bond = 4 * q + r;
        acc_init[r] = (bond < NBT) ? bbs[bond] : 0.0f;
    }

#pragma unroll 1
    for (int it = 0; it < 4; ++it) {
        const int k0 = wbase + 16 * it;

        // per-lane edge indices (lane m owns edge k0+m; same across quads)
        const int j_m = eidx[k0 + m];
        const int i_m = eidx[E_EDGES + k0 + m];
        const float* si = s_act + (size_t)i_m * IN_DIM + 4 * q;
        const float* sj = s_act + (size_t)j_m * IN_DIM + 4 * q;

        // B1 = esym^T frag: B[k-slot j<4][edge m] = esym[k0+m][4q+j]; slot4 = ones(q0)
        const bf16x4 eF = *(const bf16x4*)(esym + (size_t)(k0 + m) * EDGE_DIM + 4 * q);
        union { bf16x8 v; short s[8]; } B1;
        B1.s[0] = eF[0]; B1.s[1] = eF[1]; B1.s[2] = eF[2]; B1.s[3] = eF[3];
        B1.s[4] = one_q0; B1.s[5] = 0; B1.s[6] = 0; B1.s[7] = 0;

        f32x4v acc0 = acc_init;
        f32x4v acc1 = {0.0f, 0.0f, 0.0f, 0.0f};

#pragma unroll
        for (int g = 0; g < 16; ++g) {
            // fp32 C-init: channels 16g+4q+r of s_act[i]+s_act[j]
            const float4 a = *(const float4*)(si + 16 * g);
            const float4 b = *(const float4*)(sj + 16 * g);
            f32x4v C1;
            C1[0] = a.x + b.x; C1[1] = a.y + b.y;
            C1[2] = a.z + b.z; C1[3] = a.w + b.w;

            // A1 = Wb frag: A[row=ch-in-group m][k-slot j<4] = Wb[16g+m][4q+j];
            // slot 4 = bb[16g+m] (pairs with ones-column in B quad 0)
            const float4 w = *(const float4*)(Wb + (16 * g + m) * EDGE_DIM + 4 * q);
            const float bbv = bb[16 * g + m];
            union { bf16x8 v; unsigned u[4]; } A1;
            A1.u[0] = pack_bf16x2(w.x, w.y);
            A1.u[1] = pack_bf16x2(w.z, w.w);
            A1.u[2] = pack_bf16x2(bbv, 0.0f);
            A1.u[3] = 0u;

            // t^T tile: D[row=ch 16g+4q+r][col=edge m]
            const f32x4v P = __builtin_amdgcn_mfma_f32_16x16x32_bf16(A1.v, B1.v, C1, 0, 0, 0);

            // f = silu(t) -> directly the B2 frag for chunk g (k=ch 16g+4q+j)
            union { bf16x8 v; unsigned u[4]; } B2;
            B2.u[0] = pack_bf16x2(silu_f(P[0]), silu_f(P[1]));
            B2.u[1] = pack_bf16x2(silu_f(P[2]), silu_f(P[3]));
            B2.u[2] = 0u; B2.u[3] = 0u;

            // A2 = Wbs frag: A[row=bond m][k-slot j<4] = Wbs[m][16g+4q+j], m>=5 zero
            union { bf16x8 v; unsigned u[4]; } A2;
            if (m < NBT) {
                const float4 ws = *(const float4*)(Wbs + m * IN_DIM + 16 * g + 4 * q);
                A2.u[0] = pack_bf16x2(ws.x, ws.y);
                A2.u[1] = pack_bf16x2(ws.z, ws.w);
            } else {
                A2.u[0] = 0u; A2.u[1] = 0u;
            }
            A2.u[2] = 0u; A2.u[3] = 0u;

            if (g & 1) acc1 = __builtin_amdgcn_mfma_f32_16x16x32_bf16(A2.v, B2.v, acc1, 0, 0, 0);
            else       acc0 = __builtin_amdgcn_mfma_f32_16x16x32_bf16(A2.v, B2.v, acc0, 0, 0, 0);
        }

        const f32x4v accT = acc0 + acc1;
        // D: col m = edge k0+m, row 4q+r = bond type
        float* op = out + BONDS_OFF + (size_t)(k0 + m) * NBT;
        if (q == 0) {
            __builtin_nontemporal_store(accT[0], op + 0);
            __builtin_nontemporal_store(accT[1], op + 1);
            __builtin_nontemporal_store(accT[2], op + 2);
            __builtin_nontemporal_store(accT[3], op + 3);
        } else if (q == 1) {
            __builtin_nontemporal_store(accT[0], op + 4);
        }
    }
}

// ---------------------------------------------------------------------------
extern "C" void kernel_launch(void* const* d_in, const int* in_sizes, int n_in,
                              void* d_out, int out_size, void* d_ws, size_t ws_size,
                              hipStream_t stream) {
    const float* s   = (const float*)d_in[0];
    const float* e   = (const float*)d_in[1];
    const int*   eix = (const int*)d_in[3];
    const float* Wsh = (const float*)d_in[4];
    const float* bsh = (const float*)d_in[5];
    const float* Wb  = (const float*)d_in[6];
    const float* bbo = (const float*)d_in[7];
    const float* Wbs = (const float*)d_in[8];
    const float* bbs = (const float*)d_in[9];
    const float* Wa  = (const float*)d_in[10];
    const float* ba  = (const float*)d_in[11];
    float* out = (float*)d_out;

    char* ws = (char*)d_ws;
    float*          s_act = (float*)ws;                          // 4 MB @ 0
    unsigned short* esym  = (unsigned short*)(ws + (4u << 20));  // 8 MB @ 4 MB
    char*           tmem  = ws + (12u << 20);                    // table @ 12 MB

    const bool use_direct = (ws_size >= ((size_t)80 << 20));

    if (use_direct) {
        unsigned* T = (unsigned*)tmem;                           // 64 MB
        (void)hipMemsetAsync(T, 0x00, (size_t)DKEYS * sizeof(unsigned), stream);
        k_insert_d<<<E_EDGES / 256, 256, 0, stream>>>(eix, T);
        k12<<<N_NODES / 8, 256, 0, stream>>>(s, Wsh, bsh, Wa, ba, s_act, out);
        k_esym_d<<<E_EDGES / 256, 256, 0, stream>>>(eix, e, T, esym);
    } else {
        unsigned long long* tab = (unsigned long long*)tmem;     // 8 MB
        (void)hipMemsetAsync(tab, 0x00, TSIZE * sizeof(unsigned long long), stream);
        k_insert_h<<<E_EDGES / 256, 256, 0, stream>>>(eix, tab);
        k12<<<N_NODES / 8, 256, 0, stream>>>(s, Wsh, bsh, Wa, ba, s_act, out);
        k_esym_h<<<E_EDGES / 256, 256, 0, stream>>>(eix, e, tab, esym);
    }
    k_edges_mfma<<<1024, 256, 0, stream>>>(eix, esym, s_act, Wb, bbo, Wbs, bbs, out);
}

// Round 8
// 246.710 us; speedup vs baseline: 1.9651x; 1.0136x over previous
//
#include <hip/hip_runtime.h>
#include <hip/hip_bf16.h>

#define N_NODES   4096
#define E_EDGES   262144
#define IN_DIM    256
#define EDGE_DIM  16
#define NAF       16
#define LATENT    128
#define NBT       5

#define LATENT_OFF 0
#define ATOMS_OFF  (N_NODES * LATENT)                 // 524288
#define BONDS_OFF  (ATOMS_OFF + N_NODES * NAF)        // 589824

// hash fallback
#define TBITS 20
#define TSIZE (1u << TBITS)
#define TMASK (TSIZE - 1u)
// direct table: 2^24 u32 entries = 64 MB
#define DKEYS (1u << 24)

typedef float  f32x4  __attribute__((ext_vector_type(4)));
typedef float  f32x4v __attribute__((ext_vector_type(4)));
typedef short  bf16x8 __attribute__((ext_vector_type(8)));

__device__ __forceinline__ float silu_f(float x) {
    return x / (1.0f + __expf(-x));
}

__device__ __forceinline__ unsigned pack_bf16x2(float lo, float hi) {
    __hip_bfloat162 h = __float22bfloat162_rn(make_float2(lo, hi));
    union { __hip_bfloat162 h; unsigned u; } c;
    c.h = h;
    return c.u;
}

// ---------------------------------------------------------------------------
// K12: s_act = silu(s @ W_shared^T + b);  atoms_out = s_act @ W_atoms^T + b
// (unchanged — passed R4/R6/R7)
// ---------------------------------------------------------------------------
__global__ __launch_bounds__(256) void k12(const float* __restrict__ s,
                                           const float* __restrict__ Wsh,
                                           const float* __restrict__ bsh,
                                           const float* __restrict__ Wa,
                                           const float* __restrict__ ba,
                                           float* __restrict__ s_act,
                                           float* __restrict__ out) {
    __shared__ float sl[8][32];
    __shared__ float st[8][IN_DIM];
    const int c  = threadIdx.x;
    const int r0 = blockIdx.x * 8;

    float acc[8];
    const float bias = bsh[c];
#pragma unroll
    for (int r = 0; r < 8; ++r) acc[r] = bias;

    for (int k0 = 0; k0 < IN_DIM; k0 += 32) {
        sl[c >> 5][c & 31] = s[(r0 + (c >> 5)) * IN_DIM + k0 + (c & 31)];
        __syncthreads();

        float4 w4[8];
        const float4* wp = (const float4*)(Wsh + c * IN_DIM + k0);
#pragma unroll
        for (int q = 0; q < 8; ++q) w4[q] = wp[q];
        const float* wf = (const float*)w4;
#pragma unroll
        for (int r = 0; r < 8; ++r) {
            const float4* srow = (const float4*)sl[r];
            float a = acc[r];
#pragma unroll
            for (int q = 0; q < 8; ++q) {
                const float4 sv = srow[q];
                a += sv.x * wf[q * 4 + 0];
                a += sv.y * wf[q * 4 + 1];
                a += sv.z * wf[q * 4 + 2];
                a += sv.w * wf[q * 4 + 3];
            }
            acc[r] = a;
        }
        __syncthreads();
    }
#pragma unroll
    for (int r = 0; r < 8; ++r) {
        const float v = silu_f(acc[r]);
        s_act[(r0 + r) * IN_DIM + c] = v;
        st[r][c] = v;
    }
    __syncthreads();

    const bool active = (c < (NAF + LATENT));
    float acc2[8];
    const float bias2 = active ? ba[c] : 0.0f;
#pragma unroll
    for (int r = 0; r < 8; ++r) acc2[r] = bias2;

    if (active) {
        for (int k0 = 0; k0 < IN_DIM; k0 += 32) {
            float4 w4[8];
            const float4* wp = (const float4*)(Wa + c * IN_DIM + k0);
#pragma unroll
            for (int q = 0; q < 8; ++q) w4[q] = wp[q];
            const float* wf = (const float*)w4;
#pragma unroll
            for (int r = 0; r < 8; ++r) {
                const float4* srow = (const float4*)(st[r] + k0);
                float a = acc2[r];
#pragma unroll
                for (int q = 0; q < 8; ++q) {
                    const float4 sv = srow[q];
                    a += sv.x * wf[q * 4 + 0];
                    a += sv.y * wf[q * 4 + 1];
                    a += sv.z * wf[q * 4 + 2];
                    a += sv.w * wf[q * 4 + 3];
                }
                acc2[r] = a;
            }
        }
#pragma unroll
        for (int r = 0; r < 8; ++r) {
            const int row = r0 + r;
            if (c < NAF) out[ATOMS_OFF + row * NAF + c] = acc2[r];
            else         out[LATENT_OFF + row * LATENT + (c - NAF)] = acc2[r];
        }
    }
}

// ---------------------------------------------------------------------------
// Insert kernels: winner = max edge id per (j,i) key.
// ---------------------------------------------------------------------------
__global__ __launch_bounds__(256) void k_insert_d(const int* __restrict__ eidx,
                                                  unsigned* __restrict__ T) {
    const int k = blockIdx.x * blockDim.x + threadIdx.x;
    const unsigned j = (unsigned)eidx[k];
    const unsigned i = (unsigned)eidx[E_EDGES + k];
    atomicMax(&T[(j << 12) | i], (unsigned)(k + 1));
}

__global__ __launch_bounds__(256) void k_insert_h(const int* __restrict__ eidx,
                                                  unsigned long long* __restrict__ tab) {
    const int k = blockIdx.x * blockDim.x + threadIdx.x;
    const unsigned j = (unsigned)eidx[k];
    const unsigned i = (unsigned)eidx[E_EDGES + k];
    const unsigned key = (j << 12) | i;
    const unsigned long long mine =
        ((unsigned long long)(key + 1u) << 18) | (unsigned)k;
    unsigned h = (key * 2654435761u) >> (32 - TBITS);
    while (true) {
        unsigned long long cur = tab[h];
        if (cur == 0ULL) {
            const unsigned long long old = atomicCAS(&tab[h], 0ULL, mine);
            if (old == 0ULL) return;
            cur = old;
        }
        if ((unsigned)(cur >> 18) == key + 1u) {
            atomicMax(&tab[h], mine);
            return;
        }
        h = (h + 1u) & TMASK;
    }
}

__device__ __forceinline__ int hlookup(const unsigned long long* __restrict__ tab,
                                       unsigned key) {
    unsigned h = (key * 2654435761u) >> (32 - TBITS);
    while (true) {
        const unsigned long long cur = tab[h];
        if (cur == 0ULL) return -1;
        if ((unsigned)(cur >> 18) == key + 1u) return (int)(cur & 0x3FFFFu);
        h = (h + 1u) & TMASK;
    }
}

// ---------------------------------------------------------------------------
// K4: fully-fused zero-LDS MFMA edge kernel. One 16-edge tile per wave.
// Inlines the esym resolution (2 table lookups + e-row gather; reverse edge
// exists for only ~1.6% of edges -> exec-masked rare path).
// Transposed formulation (R7-verified): t^T = Wb @ esym^T with fp32 C-init
// s_i+s_j, bias bb folded via ones-column in slot j=4 of quad 0; then
// bonds^T = Wbs @ silu(t)^T consumed directly from D registers.
// Layouts: A[m=lane&15][k=8q+j]; B[k=8q+j][n=lane&15]; D col=lane&15(edge),
// row=4q+r. Grid: 4096 blocks x 256 = 16384 waves x 16 edges.
// ---------------------------------------------------------------------------
template <bool DIRECT>
__global__ __launch_bounds__(256, 6) void k_edges_mfma(const int* __restrict__ eidx,
                                                       const float* __restrict__ e,
                                                       const unsigned* __restrict__ T,
                                                       const unsigned long long* __restrict__ tab,
                                                       const float* __restrict__ s_act,
                                                       const float* __restrict__ Wb,
                                                       const float* __restrict__ bb,
                                                       const float* __restrict__ Wbs,
                                                       const float* __restrict__ bbs,
                                                       float* __restrict__ out) {
    const int lane = threadIdx.x & 63;
    const int wv   = threadIdx.x >> 6;
    const int m    = lane & 15;   // edge-within-tile (cols of D)
    const int q    = lane >> 4;   // quad (rows 4q+r of D)
    const int k0   = __builtin_amdgcn_readfirstlane((blockIdx.x * 4 + wv) * 16);

    const short one_q0 = (q == 0) ? (short)0x3F80 : (short)0;  // bf16(1.0)

    // acc C-init from bbs (bond = 4q+r)
    f32x4v acc_init;
#pragma unroll
    for (int r = 0; r < 4; ++r) {
        const int bond = 4 * q + r;
        acc_init[r] = (bond < NBT) ? bbs[bond] : 0.0f;
    }

    // ---- edge endpoints + winner resolution (lane m owns edge k0+m)
    const unsigned j_m = (unsigned)eidx[k0 + m];
    const unsigned i_m = (unsigned)eidx[E_EDGES + k0 + m];

    unsigned wf;       // forward winner edge id (always exists)
    int      wr;       // reverse winner edge id, -1 if absent
    if constexpr (DIRECT) {
        wf = T[(j_m << 12) | i_m] - 1u;
        const unsigned tr = T[(i_m << 12) | j_m];
        wr = (int)tr - 1;
    } else {
        wf = (unsigned)hlookup(tab, (j_m << 12) | i_m);
        wr = hlookup(tab, (i_m << 12) | j_m);
    }

    // ---- esym quarter for this lane: 0.5*(e[wf][4q..] + e[wr][4q..])
    f32x4 es = *(const f32x4*)(e + (size_t)wf * EDGE_DIM + 4 * q);
    if (wr >= 0)
        es += *(const f32x4*)(e + (size_t)wr * EDGE_DIM + 4 * q);
    es *= 0.5f;

    // B1 = esym^T frag: slots j<4 = esym[k0+m][4q+j]; slot 4 = ones(q0)
    union { bf16x8 v; short s[8]; unsigned u[4]; } B1;
    B1.u[0] = pack_bf16x2(es[0], es[1]);
    B1.u[1] = pack_bf16x2(es[2], es[3]);
    B1.s[4] = one_q0; B1.s[5] = 0;
    B1.u[3] = 0u;

    const float* si = s_act + (size_t)i_m * IN_DIM + 4 * q;
    const float* sj = s_act + (size_t)j_m * IN_DIM + 4 * q;

    f32x4v acc0 = acc_init;
    f32x4v acc1 = {0.0f, 0.0f, 0.0f, 0.0f};

#pragma unroll
    for (int g = 0; g < 16; ++g) {
        // fp32 C-init: channels 16g+4q+r of s_act[i]+s_act[j]
        const float4 a = *(const float4*)(si + 16 * g);
        const float4 b = *(const float4*)(sj + 16 * g);
        f32x4v C1;
        C1[0] = a.x + b.x; C1[1] = a.y + b.y;
        C1[2] = a.z + b.z; C1[3] = a.w + b.w;

        // A1 = Wb frag: slots j<4 = Wb[16g+m][4q+j]; slot 4 = bb[16g+m]
        const float4 w = *(const float4*)(Wb + (16 * g + m) * EDGE_DIM + 4 * q);
        const float bbv = bb[16 * g + m];
        union { bf16x8 v; unsigned u[4]; } A1;
        A1.u[0] = pack_bf16x2(w.x, w.y);
        A1.u[1] = pack_bf16x2(w.z, w.w);
        A1.u[2] = pack_bf16x2(bbv, 0.0f);
        A1.u[3] = 0u;

        const f32x4v P = __builtin_amdgcn_mfma_f32_16x16x32_bf16(A1.v, B1.v, C1, 0, 0, 0);

        // B2 frag for chunk g = silu(P) directly from D registers
        union { bf16x8 v; unsigned u[4]; } B2;
        B2.u[0] = pack_bf16x2(silu_f(P[0]), silu_f(P[1]));
        B2.u[1] = pack_bf16x2(silu_f(P[2]), silu_f(P[3]));
        B2.u[2] = 0u; B2.u[3] = 0u;

        // A2 = Wbs frag: A[row=bond m][k-slot j<4] = Wbs[m][16g+4q+j]
        union { bf16x8 v; unsigned u[4]; } A2;
        if (m < NBT) {
            const float4 ws = *(const float4*)(Wbs + m * IN_DIM + 16 * g + 4 * q);
            A2.u[0] = pack_bf16x2(ws.x, ws.y);
            A2.u[1] = pack_bf16x2(ws.z, ws.w);
        } else {
            A2.u[0] = 0u; A2.u[1] = 0u;
        }
        A2.u[2] = 0u; A2.u[3] = 0u;

        if (g & 1) acc1 = __builtin_amdgcn_mfma_f32_16x16x32_bf16(A2.v, B2.v, acc1, 0, 0, 0);
        else       acc0 = __builtin_amdgcn_mfma_f32_16x16x32_bf16(A2.v, B2.v, acc0, 0, 0, 0);
    }

    const f32x4v accT = acc0 + acc1;
    // D: col m = edge k0+m, row 4q+r = bond type
    float* op = out + BONDS_OFF + (size_t)(k0 + m) * NBT;
    if (q == 0) {
        __builtin_nontemporal_store(accT[0], op + 0);
        __builtin_nontemporal_store(accT[1], op + 1);
        __builtin_nontemporal_store(accT[2], op + 2);
        __builtin_nontemporal_store(accT[3], op + 3);
    } else if (q == 1) {
        __builtin_nontemporal_store(accT[0], op + 4);
    }
}

// ---------------------------------------------------------------------------
extern "C" void kernel_launch(void* const* d_in, const int* in_sizes, int n_in,
                              void* d_out, int out_size, void* d_ws, size_t ws_size,
                              hipStream_t stream) {
    const float* s   = (const float*)d_in[0];
    const float* e   = (const float*)d_in[1];
    const int*   eix = (const int*)d_in[3];
    const float* Wsh = (const float*)d_in[4];
    const float* bsh = (const float*)d_in[5];
    const float* Wb  = (const float*)d_in[6];
    const float* bbo = (const float*)d_in[7];
    const float* Wbs = (const float*)d_in[8];
    const float* bbs = (const float*)d_in[9];
    const float* Wa  = (const float*)d_in[10];
    const float* ba  = (const float*)d_in[11];
    float* out = (float*)d_out;

    char* ws = (char*)d_ws;
    float* s_act = (float*)ws;                 // 4 MB @ 0
    char*  tmem  = ws + (4u << 20);            // table @ 4 MB

    const bool use_direct = (ws_size >= ((size_t)72 << 20));

    if (use_direct) {
        unsigned* T = (unsigned*)tmem;                           // 64 MB
        (void)hipMemsetAsync(T, 0x00, (size_t)DKEYS * sizeof(unsigned), stream);
        k_insert_d<<<E_EDGES / 256, 256, 0, stream>>>(eix, T);
        k12<<<N_NODES / 8, 256, 0, stream>>>(s, Wsh, bsh, Wa, ba, s_act, out);
        k_edges_mfma<true><<<4096, 256, 0, stream>>>(eix, e, T, nullptr,
                                                     s_act, Wb, bbo, Wbs, bbs, out);
    } else {
        unsigned long long* tab = (unsigned long long*)tmem;     // 8 MB
        (void)hipMemsetAsync(tab, 0x00, TSIZE * sizeof(unsigned long long), stream);
        k_insert_h<<<E_EDGES / 256, 256, 0, stream>>>(eix, tab);
        k12<<<N_NODES / 8, 256, 0, stream>>>(s, Wsh, bsh, Wa, ba, s_act, out);
        k_edges_mfma<false><<<4096, 256, 0, stream>>>(eix, e, nullptr, tab,
                                                      s_act, Wb, bbo, Wbs, bbs, out);
    }
}

// Round 9
// 236.294 us; speedup vs baseline: 2.0517x; 1.0441x over previous
//
#include <hip/hip_runtime.h>
#include <hip/hip_bf16.h>

#define N_NODES   4096
#define E_EDGES   262144
#define IN_DIM    256
#define EDGE_DIM  16
#define NAF       16
#define LATENT    128
#define NBT       5

#define LATENT_OFF 0
#define ATOMS_OFF  (N_NODES * LATENT)                 // 524288
#define BONDS_OFF  (ATOMS_OFF + N_NODES * NAF)        // 589824

// hash fallback
#define TBITS 20
#define TSIZE (1u << TBITS)
#define TMASK (TSIZE - 1u)
// direct table: 2^24 u32 entries = 64 MB
#define DKEYS (1u << 24)

typedef float  f32x4  __attribute__((ext_vector_type(4)));
typedef float  f32x4v __attribute__((ext_vector_type(4)));
typedef short  bf16x8 __attribute__((ext_vector_type(8)));
typedef unsigned u32x4 __attribute__((ext_vector_type(4)));

__device__ __forceinline__ float silu_f(float x) {
    return x / (1.0f + __expf(-x));
}

// HW packed f32->bf16 RNE (gfx950 v_cvt_pk_bf16_f32), bit-trick fallback.
__device__ __forceinline__ unsigned pack_bf16x2(float lo, float hi) {
#if __has_builtin(__builtin_amdgcn_cvt_pk_bf16_f32)
    typedef __bf16 bf16x2_t __attribute__((ext_vector_type(2)));
    union { bf16x2_t v; unsigned u; } c;
    c.v = __builtin_amdgcn_cvt_pk_bf16_f32(lo, hi);
    return c.u;
#else
    union { float f; unsigned u; } a, b;
    a.f = lo; b.f = hi;
    const unsigned ra = (a.u + 0x7FFFu + ((a.u >> 16) & 1u)) >> 16;
    const unsigned rb = (b.u + 0x7FFFu + ((b.u >> 16) & 1u)) >> 16;
    return ra | (rb << 16);
#endif
}

// ---------------------------------------------------------------------------
// K12: s_act = silu(s @ W_shared^T + b);  atoms_out = s_act @ W_atoms^T + b
// (unchanged — passed R4/R6/R7/R8)
// ---------------------------------------------------------------------------
__global__ __launch_bounds__(256) void k12(const float* __restrict__ s,
                                           const float* __restrict__ Wsh,
                                           const float* __restrict__ bsh,
                                           const float* __restrict__ Wa,
                                           const float* __restrict__ ba,
                                           float* __restrict__ s_act,
                                           float* __restrict__ out) {
    __shared__ float sl[8][32];
    __shared__ float st[8][IN_DIM];
    const int c  = threadIdx.x;
    const int r0 = blockIdx.x * 8;

    float acc[8];
    const float bias = bsh[c];
#pragma unroll
    for (int r = 0; r < 8; ++r) acc[r] = bias;

    for (int k0 = 0; k0 < IN_DIM; k0 += 32) {
        sl[c >> 5][c & 31] = s[(r0 + (c >> 5)) * IN_DIM + k0 + (c & 31)];
        __syncthreads();

        float4 w4[8];
        const float4* wp = (const float4*)(Wsh + c * IN_DIM + k0);
#pragma unroll
        for (int q = 0; q < 8; ++q) w4[q] = wp[q];
        const float* wf = (const float*)w4;
#pragma unroll
        for (int r = 0; r < 8; ++r) {
            const float4* srow = (const float4*)sl[r];
            float a = acc[r];
#pragma unroll
            for (int q = 0; q < 8; ++q) {
                const float4 sv = srow[q];
                a += sv.x * wf[q * 4 + 0];
                a += sv.y * wf[q * 4 + 1];
                a += sv.z * wf[q * 4 + 2];
                a += sv.w * wf[q * 4 + 3];
            }
            acc[r] = a;
        }
        __syncthreads();
    }
#pragma unroll
    for (int r = 0; r < 8; ++r) {
        const float v = silu_f(acc[r]);
        s_act[(r0 + r) * IN_DIM + c] = v;
        st[r][c] = v;
    }
    __syncthreads();

    const bool active = (c < (NAF + LATENT));
    float acc2[8];
    const float bias2 = active ? ba[c] : 0.0f;
#pragma unroll
    for (int r = 0; r < 8; ++r) acc2[r] = bias2;

    if (active) {
        for (int k0 = 0; k0 < IN_DIM; k0 += 32) {
            float4 w4[8];
            const float4* wp = (const float4*)(Wa + c * IN_DIM + k0);
#pragma unroll
            for (int q = 0; q < 8; ++q) w4[q] = wp[q];
            const float* wf = (const float*)w4;
#pragma unroll
            for (int r = 0; r < 8; ++r) {
                const float4* srow = (const float4*)(st[r] + k0);
                float a = acc2[r];
#pragma unroll
                for (int q = 0; q < 8; ++q) {
                    const float4 sv = srow[q];
                    a += sv.x * wf[q * 4 + 0];
                    a += sv.y * wf[q * 4 + 1];
                    a += sv.z * wf[q * 4 + 2];
                    a += sv.w * wf[q * 4 + 3];
                }
                acc2[r] = a;
            }
        }
#pragma unroll
        for (int r = 0; r < 8; ++r) {
            const int row = r0 + r;
            if (c < NAF) out[ATOMS_OFF + row * NAF + c] = acc2[r];
            else         out[LATENT_OFF + row * LATENT + (c - NAF)] = acc2[r];
        }
    }
}

// ---------------------------------------------------------------------------
// k_prepack: pack Wb/bb (A1pre) and Wbs (A2pre) into MFMA A-frag records.
// Entry (g, lane): m=lane&15, q=lane>>4.
//   A1pre[g*64+lane] = { pk(Wb[16g+m][4q],Wb[..][4q+1]),
//                        pk(Wb[..][4q+2],Wb[..][4q+3]), pk(bb[16g+m],0), 0 }
//   A2pre[g*64+lane] = { pk(Wbs[m][16g+4q..]), pk(..+2,..+3), 0, 0 }  (m<5)
// ---------------------------------------------------------------------------
__global__ __launch_bounds__(256) void k_prepack(const float* __restrict__ Wb,
                                                 const float* __restrict__ bb,
                                                 const float* __restrict__ Wbs,
                                                 u32x4* __restrict__ A1pre,
                                                 u32x4* __restrict__ A2pre) {
    const int t = threadIdx.x;
#pragma unroll
    for (int ee = 0; ee < 4; ++ee) {
        const int idx  = t + 256 * ee;      // 0..1023
        const int g    = idx >> 6;
        const int lane = idx & 63;
        const int m    = lane & 15;
        const int q    = lane >> 4;

        const float4 w = *(const float4*)(Wb + (16 * g + m) * EDGE_DIM + 4 * q);
        u32x4 r1;
        r1.x = pack_bf16x2(w.x, w.y);
        r1.y = pack_bf16x2(w.z, w.w);
        r1.z = pack_bf16x2(bb[16 * g + m], 0.0f);
        r1.w = 0u;
        A1pre[idx] = r1;

        u32x4 r2;
        if (m < NBT) {
            const float4 ws = *(const float4*)(Wbs + m * IN_DIM + 16 * g + 4 * q);
            r2.x = pack_bf16x2(ws.x, ws.y);
            r2.y = pack_bf16x2(ws.z, ws.w);
        } else {
            r2.x = 0u; r2.y = 0u;
        }
        r2.z = 0u; r2.w = 0u;
        A2pre[idx] = r2;
    }
}

// ---------------------------------------------------------------------------
// Insert kernels: winner = max edge id per (j,i) key.
// ---------------------------------------------------------------------------
__global__ __launch_bounds__(256) void k_insert_d(const int* __restrict__ eidx,
                                                  unsigned* __restrict__ T) {
    const int k = blockIdx.x * blockDim.x + threadIdx.x;
    const unsigned j = (unsigned)eidx[k];
    const unsigned i = (unsigned)eidx[E_EDGES + k];
    atomicMax(&T[(j << 12) | i], (unsigned)(k + 1));
}

__global__ __launch_bounds__(256) void k_insert_h(const int* __restrict__ eidx,
                                                  unsigned long long* __restrict__ tab) {
    const int k = blockIdx.x * blockDim.x + threadIdx.x;
    const unsigned j = (unsigned)eidx[k];
    const unsigned i = (unsigned)eidx[E_EDGES + k];
    const unsigned key = (j << 12) | i;
    const unsigned long long mine =
        ((unsigned long long)(key + 1u) << 18) | (unsigned)k;
    unsigned h = (key * 2654435761u) >> (32 - TBITS);
    while (true) {
        unsigned long long cur = tab[h];
        if (cur == 0ULL) {
            const unsigned long long old = atomicCAS(&tab[h], 0ULL, mine);
            if (old == 0ULL) return;
            cur = old;
        }
        if ((unsigned)(cur >> 18) == key + 1u) {
            atomicMax(&tab[h], mine);
            return;
        }
        h = (h + 1u) & TMASK;
    }
}

__device__ __forceinline__ int hlookup(const unsigned long long* __restrict__ tab,
                                       unsigned key) {
    unsigned h = (key * 2654435761u) >> (32 - TBITS);
    while (true) {
        const unsigned long long cur = tab[h];
        if (cur == 0ULL) return -1;
        if ((unsigned)(cur >> 18) == key + 1u) return (int)(cur & 0x3FFFFu);
        h = (h + 1u) & TMASK;
    }
}

// ---------------------------------------------------------------------------
// K4: fused zero-LDS MFMA edge kernel with pre-packed weight frags.
// One 16-edge tile per wave; structure as R8 (t^T = Wb@esym^T with fp32
// C-init s_i+s_j, bb folded via ones-column; bonds^T = Wbs@silu(t)^T from
// D registers). A1/A2 frags now 16B L1-resident loads instead of runtime
// fp32 loads + SW bf16 packing (R8's VALU hog).
// ---------------------------------------------------------------------------
template <bool DIRECT>
__global__ __launch_bounds__(256, 6) void k_edges_mfma(const int* __restrict__ eidx,
                                                       const float* __restrict__ e,
                                                       const unsigned* __restrict__ T,
                                                       const unsigned long long* __restrict__ tab,
                                                       const float* __restrict__ s_act,
                                                       const u32x4* __restrict__ A1pre,
                                                       const u32x4* __restrict__ A2pre,
                                                       const float* __restrict__ bbs,
                                                       float* __restrict__ out) {
    const int lane = threadIdx.x & 63;
    const int wv   = threadIdx.x >> 6;
    const int m    = lane & 15;   // edge-within-tile (cols of D)
    const int q    = lane >> 4;   // quad (rows 4q+r of D)
    const int k0   = __builtin_amdgcn_readfirstlane((blockIdx.x * 4 + wv) * 16);

    const short one_q0 = (q == 0) ? (short)0x3F80 : (short)0;  // bf16(1.0)

    f32x4v acc_init;
#pragma unroll
    for (int r = 0; r < 4; ++r) {
        const int bond = 4 * q + r;
        acc_init[r] = (bond < NBT) ? bbs[bond] : 0.0f;
    }

    // ---- edge endpoints + winner resolution (lane m owns edge k0+m)
    const unsigned j_m = (unsigned)eidx[k0 + m];
    const unsigned i_m = (unsigned)eidx[E_EDGES + k0 + m];

    unsigned wf;
    int      wr;
    if constexpr (DIRECT) {
        wf = T[(j_m << 12) | i_m] - 1u;
        const unsigned tr = T[(i_m << 12) | j_m];
        wr = (int)tr - 1;
    } else {
        wf = (unsigned)hlookup(tab, (j_m << 12) | i_m);
        wr = hlookup(tab, (i_m << 12) | j_m);
    }

    // ---- esym quarter: 0.5*(e[wf][4q..] + e[wr][4q..])
    f32x4 es = *(const f32x4*)(e + (size_t)wf * EDGE_DIM + 4 * q);
    if (wr >= 0)
        es += *(const f32x4*)(e + (size_t)wr * EDGE_DIM + 4 * q);
    es *= 0.5f;

    union { bf16x8 v; short s[8]; unsigned u[4]; } B1;
    B1.u[0] = pack_bf16x2(es[0], es[1]);
    B1.u[1] = pack_bf16x2(es[2], es[3]);
    B1.s[4] = one_q0; B1.s[5] = 0;
    B1.u[3] = 0u;

    const float* si = s_act + (size_t)i_m * IN_DIM + 4 * q;
    const float* sj = s_act + (size_t)j_m * IN_DIM + 4 * q;
    const u32x4* a1p = A1pre + lane;
    const u32x4* a2p = A2pre + lane;

    f32x4v acc0 = acc_init;
    f32x4v acc1 = {0.0f, 0.0f, 0.0f, 0.0f};

#pragma unroll
    for (int g = 0; g < 16; ++g) {
        // fp32 C-init: channels 16g+4q+r of s_act[i]+s_act[j]
        const float4 a = *(const float4*)(si + 16 * g);
        const float4 b = *(const float4*)(sj + 16 * g);
        f32x4v C1;
        C1[0] = a.x + b.x; C1[1] = a.y + b.y;
        C1[2] = a.z + b.z; C1[3] = a.w + b.w;

        union { u32x4 r; bf16x8 v; } A1;
        A1.r = a1p[g * 64];

        const f32x4v P = __builtin_amdgcn_mfma_f32_16x16x32_bf16(A1.v, B1.v, C1, 0, 0, 0);

        union { bf16x8 v; unsigned u[4]; } B2;
        B2.u[0] = pack_bf16x2(silu_f(P[0]), silu_f(P[1]));
        B2.u[1] = pack_bf16x2(silu_f(P[2]), silu_f(P[3]));
        B2.u[2] = 0u; B2.u[3] = 0u;

        union { u32x4 r; bf16x8 v; } A2;
        A2.r = a2p[g * 64];

        if (g & 1) acc1 = __builtin_amdgcn_mfma_f32_16x16x32_bf16(A2.v, B2.v, acc1, 0, 0, 0);
        else       acc0 = __builtin_amdgcn_mfma_f32_16x16x32_bf16(A2.v, B2.v, acc0, 0, 0, 0);
    }

    const f32x4v accT = acc0 + acc1;
    float* op = out + BONDS_OFF + (size_t)(k0 + m) * NBT;
    if (q == 0) {
        __builtin_nontemporal_store(accT[0], op + 0);
        __builtin_nontemporal_store(accT[1], op + 1);
        __builtin_nontemporal_store(accT[2], op + 2);
        __builtin_nontemporal_store(accT[3], op + 3);
    } else if (q == 1) {
        __builtin_nontemporal_store(accT[0], op + 4);
    }
}

// ---------------------------------------------------------------------------
extern "C" void kernel_launch(void* const* d_in, const int* in_sizes, int n_in,
                              void* d_out, int out_size, void* d_ws, size_t ws_size,
                              hipStream_t stream) {
    const float* s   = (const float*)d_in[0];
    const float* e   = (const float*)d_in[1];
    const int*   eix = (const int*)d_in[3];
    const float* Wsh = (const float*)d_in[4];
    const float* bsh = (const float*)d_in[5];
    const float* Wb  = (const float*)d_in[6];
    const float* bbo = (const float*)d_in[7];
    const float* Wbs = (const float*)d_in[8];
    const float* bbs = (const float*)d_in[9];
    const float* Wa  = (const float*)d_in[10];
    const float* ba  = (const float*)d_in[11];
    float* out = (float*)d_out;

    char* ws = (char*)d_ws;
    float* s_act = (float*)ws;                        // 4 MB @ 0
    u32x4* A1pre = (u32x4*)(ws + (4u << 20));         // 16 KB @ 4 MB
    u32x4* A2pre = (u32x4*)(ws + (4u << 20) + 16384); // 16 KB
    char*  tmem  = ws + (5u << 20);                   // table @ 5 MB

    const bool use_direct = (ws_size >= ((size_t)72 << 20));

    k_prepack<<<1, 256, 0, stream>>>(Wb, bbo, Wbs, A1pre, A2pre);

    if (use_direct) {
        unsigned* T = (unsigned*)tmem;                           // 64 MB
        (void)hipMemsetAsync(T, 0x00, (size_t)DKEYS * sizeof(unsigned), stream);
        k_insert_d<<<E_EDGES / 256, 256, 0, stream>>>(eix, T);
        k12<<<N_NODES / 8, 256, 0, stream>>>(s, Wsh, bsh, Wa, ba, s_act, out);
        k_edges_mfma<true><<<4096, 256, 0, stream>>>(eix, e, T, nullptr,
                                                     s_act, A1pre, A2pre, bbs, out);
    } else {
        unsigned long long* tab = (unsigned long long*)tmem;     // 8 MB
        (void)hipMemsetAsync(tab, 0x00, TSIZE * sizeof(unsigned long long), stream);
        k_insert_h<<<E_EDGES / 256, 256, 0, stream>>>(eix, tab);
        k12<<<N_NODES / 8, 256, 0, stream>>>(s, Wsh, bsh, Wa, ba, s_act, out);
        k_edges_mfma<false><<<4096, 256, 0, stream>>>(eix, e, nullptr, tab,
                                                      s_act, A1pre, A2pre, bbs, out);
    }
}

// Round 10
// 228.003 us; speedup vs baseline: 2.1264x; 1.0364x over previous
//
#include <hip/hip_runtime.h>
#include <hip/hip_bf16.h>

#define N_NODES   4096
#define E_EDGES   262144
#define IN_DIM    256
#define EDGE_DIM  16
#define NAF       16
#define LATENT    128
#define NBT       5

#define LATENT_OFF 0
#define ATOMS_OFF  (N_NODES * LATENT)                 // 524288
#define BONDS_OFF  (ATOMS_OFF + N_NODES * NAF)        // 589824

// hash table: 2^20 u64 slots = 8 MB, load factor 0.25
#define TBITS 20
#define TSIZE (1u << TBITS)
#define TMASK (TSIZE - 1u)

typedef float    f32x4  __attribute__((ext_vector_type(4)));
typedef float    f32x4v __attribute__((ext_vector_type(4)));
typedef short    bf16x8 __attribute__((ext_vector_type(8)));
typedef unsigned u32x2  __attribute__((ext_vector_type(2)));
typedef unsigned u32x4  __attribute__((ext_vector_type(4)));

__device__ __forceinline__ float silu_f(float x) {
    return x / (1.0f + __expf(-x));
}

// HW packed f32->bf16 RNE (gfx950 v_cvt_pk_bf16_f32), bit-trick fallback.
__device__ __forceinline__ unsigned pack_bf16x2(float lo, float hi) {
#if __has_builtin(__builtin_amdgcn_cvt_pk_bf16_f32)
    typedef __bf16 bf16x2_t __attribute__((ext_vector_type(2)));
    union { bf16x2_t v; unsigned u; } c;
    c.v = __builtin_amdgcn_cvt_pk_bf16_f32(lo, hi);
    return c.u;
#else
    union { float f; unsigned u; } a, b;
    a.f = lo; b.f = hi;
    const unsigned ra = (a.u + 0x7FFFu + ((a.u >> 16) & 1u)) >> 16;
    const unsigned rb = (b.u + 0x7FFFu + ((b.u >> 16) & 1u)) >> 16;
    return ra | (rb << 16);
#endif
}

__device__ __forceinline__ float bf_lo(unsigned u) {
    union { unsigned x; float f; } c; c.x = u << 16; return c.f;
}
__device__ __forceinline__ float bf_hi(unsigned u) {
    union { unsigned x; float f; } c; c.x = u & 0xFFFF0000u; return c.f;
}

__device__ __forceinline__ int hlookup(const unsigned long long* __restrict__ tab,
                                       unsigned key) {
    unsigned h = (key * 2654435761u) >> (32 - TBITS);
    while (true) {
        const unsigned long long cur = tab[h];
        if (cur == 0ULL) return -1;
        if ((unsigned)(cur >> 18) == key + 1u) return (int)(cur & 0x3FFFFu);
        h = (h + 1u) & TMASK;
    }
}

// ---------------------------------------------------------------------------
// k_prep: ONE kernel for all preparation.
//   blocks 0..511    : k12 — s_act(bf16) = silu(s@Wsh^T+b); atoms/latent out
//   blocks 512..1535 : hash insert (winner = max edge id per (j,i) key)
//   block  1536      : prepack Wb/bb and Wbs into MFMA A-frag records
// ---------------------------------------------------------------------------
__global__ __launch_bounds__(256) void k_prep(const float* __restrict__ s,
                                              const float* __restrict__ Wsh,
                                              const float* __restrict__ bsh,
                                              const float* __restrict__ Wa,
                                              const float* __restrict__ ba,
                                              const int* __restrict__ eidx,
                                              const float* __restrict__ Wb,
                                              const float* __restrict__ bb,
                                              const float* __restrict__ Wbs,
                                              unsigned* __restrict__ sact16,
                                              unsigned long long* __restrict__ tab,
                                              u32x4* __restrict__ A1pre,
                                              u32x4* __restrict__ A2pre,
                                              float* __restrict__ out) {
    __shared__ float sl[8][32];
    __shared__ float st[8][IN_DIM];
    const int blk = blockIdx.x;
    const int c   = threadIdx.x;

    if (blk >= 512) {
        if (blk < 1536) {
            // ---- hash insert: slot u64 = ((key+1)<<18)|edge, winner = max edge
            const int k = (blk - 512) * 256 + c;
            const unsigned j = (unsigned)eidx[k];
            const unsigned i = (unsigned)eidx[E_EDGES + k];
            const unsigned key = (j << 12) | i;
            const unsigned long long mine =
                ((unsigned long long)(key + 1u) << 18) | (unsigned)k;
            unsigned h = (key * 2654435761u) >> (32 - TBITS);
            while (true) {
                unsigned long long cur = tab[h];
                if (cur == 0ULL) {
                    const unsigned long long old = atomicCAS(&tab[h], 0ULL, mine);
                    if (old == 0ULL) return;
                    cur = old;
                }
                if ((unsigned)(cur >> 18) == key + 1u) {
                    atomicMax(&tab[h], mine);
                    return;
                }
                h = (h + 1u) & TMASK;
            }
        } else {
            // ---- prepack A-frags (1024 entries, 4 per thread)
#pragma unroll
            for (int ee = 0; ee < 4; ++ee) {
                const int idx  = c + 256 * ee;
                const int g    = idx >> 6;
                const int lane = idx & 63;
                const int m    = lane & 15;
                const int q    = lane >> 4;

                const float4 w = *(const float4*)(Wb + (16 * g + m) * EDGE_DIM + 4 * q);
                u32x4 r1;
                r1.x = pack_bf16x2(w.x, w.y);
                r1.y = pack_bf16x2(w.z, w.w);
                r1.z = pack_bf16x2(bb[16 * g + m], 0.0f);
                r1.w = 0u;
                A1pre[idx] = r1;

                u32x4 r2;
                if (m < NBT) {
                    const float4 ws = *(const float4*)(Wbs + m * IN_DIM + 16 * g + 4 * q);
                    r2.x = pack_bf16x2(ws.x, ws.y);
                    r2.y = pack_bf16x2(ws.z, ws.w);
                } else {
                    r2.x = 0u; r2.y = 0u;
                }
                r2.z = 0u; r2.w = 0u;
                A2pre[idx] = r2;
            }
        }
        return;
    }

    // ---- k12 body: rows r0..r0+7
    const int r0 = blk * 8;

    float acc[8];
    const float bias = bsh[c];
#pragma unroll
    for (int r = 0; r < 8; ++r) acc[r] = bias;

    for (int k0 = 0; k0 < IN_DIM; k0 += 32) {
        sl[c >> 5][c & 31] = s[(r0 + (c >> 5)) * IN_DIM + k0 + (c & 31)];
        __syncthreads();

        float4 w4[8];
        const float4* wp = (const float4*)(Wsh + c * IN_DIM + k0);
#pragma unroll
        for (int q = 0; q < 8; ++q) w4[q] = wp[q];
        const float* wf = (const float*)w4;
#pragma unroll
        for (int r = 0; r < 8; ++r) {
            const float4* srow = (const float4*)sl[r];
            float a = acc[r];
#pragma unroll
            for (int q = 0; q < 8; ++q) {
                const float4 sv = srow[q];
                a += sv.x * wf[q * 4 + 0];
                a += sv.y * wf[q * 4 + 1];
                a += sv.z * wf[q * 4 + 2];
                a += sv.w * wf[q * 4 + 3];
            }
            acc[r] = a;
        }
        __syncthreads();
    }
#pragma unroll
    for (int r = 0; r < 8; ++r) st[r][c] = silu_f(acc[r]);
    __syncthreads();

    // bf16-packed s_act (u32 = ch pair); coalesced 512 B per row
    if (c < 128) {
#pragma unroll
        for (int r = 0; r < 8; ++r)
            sact16[(size_t)(r0 + r) * 128 + c] =
                pack_bf16x2(st[r][2 * c], st[r][2 * c + 1]);
    }

    // ---- atoms/latent: cols 0..143 from st
    const bool active = (c < (NAF + LATENT));
    float acc2[8];
    const float bias2 = active ? ba[c] : 0.0f;
#pragma unroll
    for (int r = 0; r < 8; ++r) acc2[r] = bias2;

    if (active) {
        for (int k0 = 0; k0 < IN_DIM; k0 += 32) {
            float4 w4[8];
            const float4* wp = (const float4*)(Wa + c * IN_DIM + k0);
#pragma unroll
            for (int q = 0; q < 8; ++q) w4[q] = wp[q];
            const float* wf = (const float*)w4;
#pragma unroll
            for (int r = 0; r < 8; ++r) {
                const float4* srow = (const float4*)(st[r] + k0);
                float a = acc2[r];
#pragma unroll
                for (int q = 0; q < 8; ++q) {
                    const float4 sv = srow[q];
                    a += sv.x * wf[q * 4 + 0];
                    a += sv.y * wf[q * 4 + 1];
                    a += sv.z * wf[q * 4 + 2];
                    a += sv.w * wf[q * 4 + 3];
                }
                acc2[r] = a;
            }
        }
#pragma unroll
        for (int r = 0; r < 8; ++r) {
            const int row = r0 + r;
            if (c < NAF) out[ATOMS_OFF + row * NAF + c] = acc2[r];
            else         out[LATENT_OFF + row * LATENT + (c - NAF)] = acc2[r];
        }
    }
}

// ---------------------------------------------------------------------------
// K4: fused zero-LDS MFMA edge kernel (R9 structure) with:
//  - hash-table probes (8 MB, ~L2-resident) instead of 64 MB direct table
//  - bf16 s_act gathers (8 B/lane/g) unpacked to exact fp32 C-init
//  - loads grouped in quarters to force memory-level parallelism
// ---------------------------------------------------------------------------
__global__ __launch_bounds__(256, 6) void k_edges_mfma(const int* __restrict__ eidx,
                                                       const float* __restrict__ e,
                                                       const unsigned long long* __restrict__ tab,
                                                       const unsigned* __restrict__ sact16,
                                                       const u32x4* __restrict__ A1pre,
                                                       const u32x4* __restrict__ A2pre,
                                                       const float* __restrict__ bbs,
                                                       float* __restrict__ out) {
    const int lane = threadIdx.x & 63;
    const int wv   = threadIdx.x >> 6;
    const int m    = lane & 15;   // edge-within-tile (cols of D)
    const int q    = lane >> 4;   // quad (rows 4q+r of D)
    const int k0   = __builtin_amdgcn_readfirstlane((blockIdx.x * 4 + wv) * 16);

    const short one_q0 = (q == 0) ? (short)0x3F80 : (short)0;  // bf16(1.0)

    f32x4v acc_init;
#pragma unroll
    for (int r = 0; r < 4; ++r) {
        const int bond = 4 * q + r;
        acc_init[r] = (bond < NBT) ? bbs[bond] : 0.0f;
    }

    // ---- edge endpoints + winner resolution (lane m owns edge k0+m)
    const unsigned j_m = (unsigned)eidx[k0 + m];
    const unsigned i_m = (unsigned)eidx[E_EDGES + k0 + m];

    const unsigned wf = (unsigned)hlookup(tab, (j_m << 12) | i_m);  // exists
    const int      wr = hlookup(tab, (i_m << 12) | j_m);            // -1 if absent

    // ---- esym quarter: 0.5*(e[wf][4q..] + e[wr][4q..])
    f32x4 es = *(const f32x4*)(e + (size_t)wf * EDGE_DIM + 4 * q);
    if (wr >= 0)
        es += *(const f32x4*)(e + (size_t)wr * EDGE_DIM + 4 * q);
    es *= 0.5f;

    union { bf16x8 v; short s[8]; unsigned u[4]; } B1;
    B1.u[0] = pack_bf16x2(es[0], es[1]);
    B1.u[1] = pack_bf16x2(es[2], es[3]);
    B1.s[4] = one_q0; B1.s[5] = 0;
    B1.u[3] = 0u;

    // bf16 s_act word pointers: word idx = row*128 + 8g + 2q
    const unsigned* si = sact16 + (size_t)i_m * 128 + 2 * q;
    const unsigned* sj = sact16 + (size_t)j_m * 128 + 2 * q;
    const u32x4* a1p = A1pre + lane;
    const u32x4* a2p = A2pre + lane;

    f32x4v acc0 = acc_init;
    f32x4v acc1 = {0.0f, 0.0f, 0.0f, 0.0f};

#pragma unroll
    for (int qt = 0; qt < 4; ++qt) {
        // issue all 8 s_act loads of this quarter first (MLP)
        u32x2 vi[4], vj[4];
#pragma unroll
        for (int t = 0; t < 4; ++t) {
            const int g = 4 * qt + t;
            vi[t] = *(const u32x2*)(si + 8 * g);
            vj[t] = *(const u32x2*)(sj + 8 * g);
        }
#pragma unroll
        for (int t = 0; t < 4; ++t) {
            const int g = 4 * qt + t;
            // exact fp32 C-init: channels 16g+4q+r of s_i + s_j
            f32x4v C1;
            C1[0] = bf_lo(vi[t].x) + bf_lo(vj[t].x);
            C1[1] = bf_hi(vi[t].x) + bf_hi(vj[t].x);
            C1[2] = bf_lo(vi[t].y) + bf_lo(vj[t].y);
            C1[3] = bf_hi(vi[t].y) + bf_hi(vj[t].y);

            union { u32x4 r; bf16x8 v; } A1;
            A1.r = a1p[g * 64];

            const f32x4v P = __builtin_amdgcn_mfma_f32_16x16x32_bf16(A1.v, B1.v, C1, 0, 0, 0);

            union { bf16x8 v; unsigned u[4]; } B2;
            B2.u[0] = pack_bf16x2(silu_f(P[0]), silu_f(P[1]));
            B2.u[1] = pack_bf16x2(silu_f(P[2]), silu_f(P[3]));
            B2.u[2] = 0u; B2.u[3] = 0u;

            union { u32x4 r; bf16x8 v; } A2;
            A2.r = a2p[g * 64];

            if (g & 1) acc1 = __builtin_amdgcn_mfma_f32_16x16x32_bf16(A2.v, B2.v, acc1, 0, 0, 0);
            else       acc0 = __builtin_amdgcn_mfma_f32_16x16x32_bf16(A2.v, B2.v, acc0, 0, 0, 0);
        }
    }

    const f32x4v accT = acc0 + acc1;
    float* op = out + BONDS_OFF + (size_t)(k0 + m) * NBT;
    if (q == 0) {
        __builtin_nontemporal_store(accT[0], op + 0);
        __builtin_nontemporal_store(accT[1], op + 1);
        __builtin_nontemporal_store(accT[2], op + 2);
        __builtin_nontemporal_store(accT[3], op + 3);
    } else if (q == 1) {
        __builtin_nontemporal_store(accT[0], op + 4);
    }
}

// ---------------------------------------------------------------------------
extern "C" void kernel_launch(void* const* d_in, const int* in_sizes, int n_in,
                              void* d_out, int out_size, void* d_ws, size_t ws_size,
                              hipStream_t stream) {
    const float* s   = (const float*)d_in[0];
    const float* e   = (const float*)d_in[1];
    const int*   eix = (const int*)d_in[3];
    const float* Wsh = (const float*)d_in[4];
    const float* bsh = (const float*)d_in[5];
    const float* Wb  = (const float*)d_in[6];
    const float* bbo = (const float*)d_in[7];
    const float* Wbs = (const float*)d_in[8];
    const float* bbs = (const float*)d_in[9];
    const float* Wa  = (const float*)d_in[10];
    const float* ba  = (const float*)d_in[11];
    float* out = (float*)d_out;

    char* ws = (char*)d_ws;
    unsigned*           sact16 = (unsigned*)ws;                   // 2 MB @ 0
    u32x4*              A1pre  = (u32x4*)(ws + (2u << 20));       // 16 KB
    u32x4*              A2pre  = (u32x4*)(ws + (2u << 20) + 16384);
    unsigned long long* tab    = (unsigned long long*)(ws + (3u << 20)); // 8 MB

    (void)hipMemsetAsync(tab, 0x00, TSIZE * sizeof(unsigned long long), stream);

    k_prep<<<1537, 256, 0, stream>>>(s, Wsh, bsh, Wa, ba, eix, Wb, bbo, Wbs,
                                     sact16, tab, A1pre, A2pre, out);
    k_edges_mfma<<<4096, 256, 0, stream>>>(eix, e, tab, sact16,
                                           A1pre, A2pre, bbs, out);
}